// Round 1
// baseline (677.012 us; speedup 1.0000x reference)
//
#include <hip/hip_runtime.h>
#include <cmath>

#define NB 64
#define NM 1024
#define NE 1024
#define NH 8
#define NHD 128
#define NMID 64
#define CELU_ALPHA 1.3f

__device__ __forceinline__ float celuf(float x) {
    return x > 0.f ? x : CELU_ALPHA * expm1f(x / CELU_ALPHA);
}

// ---------------------------------------------------------------------------
// A1: qpre = celu(h @ Wq + bq), v1pre = celu(h @ Wv1 + bv1)
// grid 64 = (mat 2) x (32-col chunks), block 256
// ---------------------------------------------------------------------------
__global__ __launch_bounds__(256) void a1_qv_gemm(
    const float* __restrict__ h, const float* __restrict__ Wq, const float* __restrict__ bq,
    const float* __restrict__ Wv1, const float* __restrict__ bv1,
    float* __restrict__ qpre, float* __restrict__ v1pre)
{
    const int t = threadIdx.x;
    const int mat = blockIdx.x >> 5;
    const int cc = (blockIdx.x & 31) * 32;
    const float* __restrict__ W = mat ? Wv1 : Wq;
    const float* __restrict__ bias = mat ? bv1 : bq;
    float* __restrict__ out = mat ? v1pre : qpre;

    __shared__ float hs[64][68];
    const int col = cc + (t & 31);
    const int rowg = t >> 5;

    float acc[8];
#pragma unroll
    for (int j = 0; j < 8; ++j) acc[j] = 0.f;

    for (int k0 = 0; k0 < 1024; k0 += 64) {
        {
            const int r = t >> 2, b0 = (t & 3) * 16;
#pragma unroll
            for (int u = 0; u < 4; ++u) {
                float4 v = *(const float4*)&h[r * 1024 + k0 + b0 + 4 * u];
                *(float4*)&hs[r][b0 + 4 * u] = v;
            }
        }
        __syncthreads();
#pragma unroll 4
        for (int kl = 0; kl < 64; ++kl) {
            const float wv = W[(size_t)(k0 + kl) * 1024 + col];
#pragma unroll
            for (int j = 0; j < 8; ++j)
                acc[j] = fmaf(hs[rowg * 8 + j][kl], wv, acc[j]);
        }
        __syncthreads();
    }
    const float bv = bias[col];
#pragma unroll
    for (int j = 0; j < 8; ++j)
        out[(rowg * 8 + j) * 1024 + col] = celuf(acc[j] + bv);
}

// ---------------------------------------------------------------------------
// A2: in-place group norm (G=8, 128 ch/group, ddof=1). grid 128 = (mat 2)x(row 64)
// ---------------------------------------------------------------------------
__global__ __launch_bounds__(256) void a2_groupnorm(
    float* __restrict__ qpre, float* __restrict__ v1pre,
    const float* __restrict__ gnw_q, const float* __restrict__ gnb_q,
    const float* __restrict__ gnw_v, const float* __restrict__ gnb_v)
{
    const int t = threadIdx.x;
    const int mat = blockIdx.x >> 6;
    const int row = blockIdx.x & 63;
    float* __restrict__ buf = mat ? v1pre : qpre;
    const float* __restrict__ gw = mat ? gnw_v : gnw_q;
    const float* __restrict__ gb = mat ? gnb_v : gnb_q;

    float4 x = *(const float4*)&buf[row * 1024 + t * 4];
    float s = x.x + x.y + x.z + x.w;
#pragma unroll
    for (int m = 16; m >= 1; m >>= 1) s += __shfl_xor(s, m);
    const float mean = s * (1.f / 128.f);
    const float d0 = x.x - mean, d1 = x.y - mean, d2 = x.z - mean, d3 = x.w - mean;
    float ss = d0 * d0 + d1 * d1 + d2 * d2 + d3 * d3;
#pragma unroll
    for (int m = 16; m >= 1; m >>= 1) ss += __shfl_xor(ss, m);
    const float inv = rsqrtf(ss * (1.f / 127.f) + 1e-5f);
    const float4 w4 = *(const float4*)&gw[t * 4];
    const float4 b4 = *(const float4*)&gb[t * 4];
    float4 y;
    y.x = d0 * inv * w4.x + b4.x;
    y.y = d1 * inv * w4.y + b4.y;
    y.z = d2 * inv * w4.z + b4.z;
    y.w = d3 * inv * w4.w + b4.w;
    *(float4*)&buf[row * 1024 + t * 4] = y;
}

// ---------------------------------------------------------------------------
// B: per-(b,h) attention core. grid 512, block 256 (4 waves)
// ---------------------------------------------------------------------------
__global__ __launch_bounds__(256) void b_attention(
    const float* __restrict__ pat, const float* __restrict__ mask,
    const float* __restrict__ q, const float* __restrict__ v1,
    const float* __restrict__ Wb, const float* __restrict__ bb,
    const float* __restrict__ Ws, const float* __restrict__ bs,
    const float* __restrict__ Wc, const float* __restrict__ bc,
    float* __restrict__ att_out)
{
    const int t = threadIdx.x;
    const int b = blockIdx.x >> 3;
    const int h = blockIdx.x & 7;
    const int w = t >> 6;
    const int lane = t & 63;
    const int c = lane & 7;        // col group: cols c*8..c*8+7
    const int rg = lane >> 3;      // 0..7

    __shared__ float wbq[128][64];     // q-scaled Wb
    __shared__ float ktile[64][132];   // padded: conflict-free reads
    __shared__ float s_lds[1024];
    __shared__ float mask_lds[1024];
    __shared__ float q_lds[128];
    __shared__ float ws_lds[64];
    __shared__ float bb_lds[64];
    __shared__ float pool_red[4][64];
    __shared__ float att_red[4][128];
    __shared__ float pool2[64];
    __shared__ float red4[4];

    if (t < 128) q_lds[t] = q[b * 1024 + h * 128 + t];
    if (t >= 128 && t < 192) {
        ws_lds[t - 128] = Ws[h * 64 + (t - 128)];
        bb_lds[t - 128] = bb[h * 64 + (t - 128)];
    }
    *(float4*)&mask_lds[t * 4] = *(const float4*)&mask[b * 1024 + t * 4];
    __syncthreads();

#pragma unroll 8
    for (int u = 0; u < 32; ++u) {
        const int idx = t + 256 * u;
        wbq[idx >> 6][idx & 63] = q_lds[idx >> 6] * Wb[h * 8192 + idx];
    }

    float pool_part[8];
#pragma unroll
    for (int j = 0; j < 8; ++j) pool_part[j] = 0.f;
    const float bsh = bs[h];

    const float* __restrict__ patk = pat + (size_t)b * NM * 2048 + h * 128;

    for (int mt = 0; mt < 16; ++mt) {
        __syncthreads();
#pragma unroll
        for (int u = 0; u < 8; ++u) {
            const int idx4 = t + 256 * u;
            const int r = idx4 >> 5, iv = idx4 & 31;
            float4 v = *(const float4*)&patk[(size_t)(mt * 64 + r) * 2048 + iv * 4];
            *(float4*)&ktile[r][iv * 4] = v;
        }
        __syncthreads();

        float acc0[8], acc1[8];
#pragma unroll
        for (int j = 0; j < 8; ++j) { acc0[j] = 0.f; acc1[j] = 0.f; }

#pragma unroll 2
        for (int i4 = 0; i4 < 32; ++i4) {
            const float4 ka = *(const float4*)&ktile[w * 16 + rg][i4 * 4];
            const float4 kb = *(const float4*)&ktile[w * 16 + rg + 8][i4 * 4];
            const float kav[4] = {ka.x, ka.y, ka.z, ka.w};
            const float kbv[4] = {kb.x, kb.y, kb.z, kb.w};
#pragma unroll
            for (int di = 0; di < 4; ++di) {
                const float4 w0 = *(const float4*)&wbq[i4 * 4 + di][c * 8];
                const float4 w1 = *(const float4*)&wbq[i4 * 4 + di][c * 8 + 4];
                acc0[0] = fmaf(kav[di], w0.x, acc0[0]);
                acc0[1] = fmaf(kav[di], w0.y, acc0[1]);
                acc0[2] = fmaf(kav[di], w0.z, acc0[2]);
                acc0[3] = fmaf(kav[di], w0.w, acc0[3]);
                acc0[4] = fmaf(kav[di], w1.x, acc0[4]);
                acc0[5] = fmaf(kav[di], w1.y, acc0[5]);
                acc0[6] = fmaf(kav[di], w1.z, acc0[6]);
                acc0[7] = fmaf(kav[di], w1.w, acc0[7]);
                acc1[0] = fmaf(kbv[di], w0.x, acc1[0]);
                acc1[1] = fmaf(kbv[di], w0.y, acc1[1]);
                acc1[2] = fmaf(kbv[di], w0.z, acc1[2]);
                acc1[3] = fmaf(kbv[di], w0.w, acc1[3]);
                acc1[4] = fmaf(kbv[di], w1.x, acc1[4]);
                acc1[5] = fmaf(kbv[di], w1.y, acc1[5]);
                acc1[6] = fmaf(kbv[di], w1.z, acc1[6]);
                acc1[7] = fmaf(kbv[di], w1.w, acc1[7]);
            }
        }

        // epilogue: relu + bias, score partial, pool partial
#pragma unroll
        for (int dr = 0; dr < 2; ++dr) {
            const int m = mt * 64 + w * 16 + rg + 8 * dr;
            const float mk = mask_lds[m];
            float sp = 0.f;
#pragma unroll
            for (int j = 0; j < 8; ++j) {
                float a = (dr ? acc1[j] : acc0[j]) + bb_lds[c * 8 + j];
                a = fmaxf(a, 0.f);
                sp = fmaf(a, ws_lds[c * 8 + j], sp);
                pool_part[j] = fmaf(a, mk, pool_part[j]);
            }
            sp += __shfl_xor(sp, 1);
            sp += __shfl_xor(sp, 2);
            sp += __shfl_xor(sp, 4);
            if (c == 0) s_lds[m] = sp;
        }
    }

    // reduce pool across row-groups (rg bits = lane bits 3..5)
#pragma unroll
    for (int j = 0; j < 8; ++j) {
        float p = pool_part[j];
        p += __shfl_xor(p, 8);
        p += __shfl_xor(p, 16);
        p += __shfl_xor(p, 32);
        pool_part[j] = p;
    }
    if (lane < 8) {
#pragma unroll
        for (int j = 0; j < 8; ++j) pool_red[w][lane * 8 + j] = pool_part[j];
    }

    // mask sum
    float msp = 0.f;
#pragma unroll
    for (int u = 0; u < 4; ++u) msp += mask_lds[t + 256 * u];
#pragma unroll
    for (int m = 32; m >= 1; m >>= 1) msp += __shfl_xor(msp, m);
    if (lane == 0) red4[w] = msp;
    __syncthreads();                               // SYNC1
    const float msum = red4[0] + red4[1] + red4[2] + red4[3];

    // masked scores + max
    float sc[4];
    float mymax = -3.0e38f;
#pragma unroll
    for (int u = 0; u < 4; ++u) {
        const int m = t + 256 * u;
        const float v = (mask_lds[m] == 0.f) ? -1e9f : (s_lds[m] + bsh);
        sc[u] = v;
        mymax = fmaxf(mymax, v);
    }
#pragma unroll
    for (int m = 32; m >= 1; m >>= 1) mymax = fmaxf(mymax, __shfl_xor(mymax, m));
    __syncthreads();                               // SYNC2 (red4 reuse)
    if (lane == 0) red4[w] = mymax;
    if (t < 64)
        pool2[t] = (pool_red[0][t] + pool_red[1][t] + pool_red[2][t] + pool_red[3][t]) / msum;
    __syncthreads();                               // SYNC3
    const float gmax = fmaxf(fmaxf(red4[0], red4[1]), fmaxf(red4[2], red4[3]));
    float esp = 0.f;
#pragma unroll
    for (int u = 0; u < 4; ++u) {
        const float e = expf(sc[u] - gmax);
        s_lds[t + 256 * u] = e;
        esp += e;
    }
#pragma unroll
    for (int m = 32; m >= 1; m >>= 1) esp += __shfl_xor(esp, m);
    __syncthreads();                               // SYNC4 (red4 reuse)
    if (lane == 0) red4[w] = esp;
    __syncthreads();                               // SYNC5
    const float einv = 1.f / (red4[0] + red4[1] + red4[2] + red4[3]);
#pragma unroll
    for (int u = 0; u < 4; ++u) s_lds[t + 256 * u] *= einv;
    __syncthreads();                               // SYNC6: p ready

    // pass 2: att[d] = sum_m p[m] * v2[m,d]
    const int dg = t & 31, rwg = t >> 5;
    const float* __restrict__ patv = pat + (size_t)b * NM * 2048 + 1024 + h * 128;
    float4 a4 = {0.f, 0.f, 0.f, 0.f};
#pragma unroll 2
    for (int mt = 0; mt < 128; ++mt) {
        const int m = mt * 8 + rwg;
        const float4 v = *(const float4*)&patv[(size_t)m * 2048 + dg * 4];
        const float pw = s_lds[m];
        a4.x = fmaf(pw, v.x, a4.x);
        a4.y = fmaf(pw, v.y, a4.y);
        a4.z = fmaf(pw, v.z, a4.z);
        a4.w = fmaf(pw, v.w, a4.w);
    }
    a4.x += __shfl_xor(a4.x, 32);
    a4.y += __shfl_xor(a4.y, 32);
    a4.z += __shfl_xor(a4.z, 32);
    a4.w += __shfl_xor(a4.w, 32);
    if (lane < 32) *(float4*)&att_red[w][dg * 4] = a4;
    __syncthreads();

    if (t < 128) {
        const int d = t;
        const float attv = att_red[0][d] + att_red[1][d] + att_red[2][d] + att_red[3][d];
        float ac = bc[h * 128 + d];
#pragma unroll 8
        for (int o = 0; o < 64; ++o)
            ac = fmaf(pool2[o], Wc[h * 8192 + o * 128 + d], ac);
        const float sig = 1.f / (1.f + expf(-ac));
        att_out[b * 1024 + h * 128 + d] = attv * v1[b * 1024 + h * 128 + d] * sig;
    }
}

// ---------------------------------------------------------------------------
// C1: partial[kq] = x_kq @ Wt_kq  (K split in 4). grid 128 = (kq 4)x(32-col chunks)
// ---------------------------------------------------------------------------
__global__ __launch_bounds__(256) void c1_gemm(
    const float* __restrict__ h, const float* __restrict__ att,
    const float* __restrict__ Wt, float* __restrict__ part)
{
    const int t = threadIdx.x;
    const int kq = blockIdx.x >> 5;
    const int cc = (blockIdx.x & 31) * 32;
    const int col = cc + (t & 31);
    const int rowg = t >> 5;
    const float* __restrict__ x = (kq < 2) ? h : att;
    const int kbase = (kq & 1) * 512;

    __shared__ float xs[64][68];
    float acc[8];
#pragma unroll
    for (int j = 0; j < 8; ++j) acc[j] = 0.f;

    for (int k0 = 0; k0 < 512; k0 += 64) {
        {
            const int r = t >> 2, b0 = (t & 3) * 16;
#pragma unroll
            for (int u = 0; u < 4; ++u) {
                float4 v = *(const float4*)&x[r * 1024 + kbase + k0 + b0 + 4 * u];
                *(float4*)&xs[r][b0 + 4 * u] = v;
            }
        }
        __syncthreads();
#pragma unroll 4
        for (int kl = 0; kl < 64; ++kl) {
            const float wv = Wt[(size_t)(kq * 512 + k0 + kl) * 1024 + col];
#pragma unroll
            for (int j = 0; j < 8; ++j)
                acc[j] = fmaf(xs[rowg * 8 + j][kl], wv, acc[j]);
        }
        __syncthreads();
    }
#pragma unroll
    for (int j = 0; j < 8; ++j)
        part[kq * 65536 + (rowg * 8 + j) * 1024 + col] = acc[j];
}

// ---------------------------------------------------------------------------
// C2: sum partials + bt, LayerNorm (ddof=0). grid 64 rows, block 256
// ---------------------------------------------------------------------------
__global__ __launch_bounds__(256) void c2_ln(
    const float* __restrict__ part, const float* __restrict__ bt,
    const float* __restrict__ lnw, const float* __restrict__ lnb,
    float* __restrict__ out)
{
    const int t = threadIdx.x;
    const int row = blockIdx.x;
    const int w = t >> 6, lane = t & 63;
    __shared__ float red[4];

    float4 v = *(const float4*)&bt[t * 4];
#pragma unroll
    for (int qd = 0; qd < 4; ++qd) {
        const float4 p = *(const float4*)&part[qd * 65536 + row * 1024 + t * 4];
        v.x += p.x; v.y += p.y; v.z += p.z; v.w += p.w;
    }
    float s = v.x + v.y + v.z + v.w;
#pragma unroll
    for (int m = 32; m >= 1; m >>= 1) s += __shfl_xor(s, m);
    if (lane == 0) red[w] = s;
    __syncthreads();
    const float mean = (red[0] + red[1] + red[2] + red[3]) * (1.f / 1024.f);
    __syncthreads();
    const float d0 = v.x - mean, d1 = v.y - mean, d2 = v.z - mean, d3 = v.w - mean;
    float ss = d0 * d0 + d1 * d1 + d2 * d2 + d3 * d3;
#pragma unroll
    for (int m = 32; m >= 1; m >>= 1) ss += __shfl_xor(ss, m);
    if (lane == 0) red[w] = ss;
    __syncthreads();
    const float var = (red[0] + red[1] + red[2] + red[3]) * (1.f / 1024.f);
    const float inv = rsqrtf(var + 1e-5f);
    const float4 w4 = *(const float4*)&lnw[t * 4];
    const float4 b4 = *(const float4*)&lnb[t * 4];
    float4 y;
    y.x = d0 * inv * w4.x + b4.x;
    y.y = d1 * inv * w4.y + b4.y;
    y.z = d2 * inv * w4.z + b4.z;
    y.w = d3 * inv * w4.w + b4.w;
    *(float4*)&out[row * 1024 + t * 4] = y;
}

// ---------------------------------------------------------------------------
extern "C" void kernel_launch(void* const* d_in, const int* in_sizes, int n_in,
                              void* d_out, int out_size, void* d_ws, size_t ws_size,
                              hipStream_t stream)
{
    const float* h_state  = (const float*)d_in[0];
    // d_in[1] = att_feats: UNUSED by the reference — never read (saves 256 MB)
    const float* att_mask = (const float*)d_in[2];
    const float* pat      = (const float*)d_in[3];
    const float* Wq       = (const float*)d_in[4];
    const float* bq       = (const float*)d_in[5];
    const float* gnw_q    = (const float*)d_in[6];
    const float* gnb_q    = (const float*)d_in[7];
    const float* Wv1      = (const float*)d_in[8];
    const float* bv1      = (const float*)d_in[9];
    const float* gnw_v1   = (const float*)d_in[10];
    const float* gnb_v1   = (const float*)d_in[11];
    const float* Wb       = (const float*)d_in[12];
    const float* bb       = (const float*)d_in[13];
    const float* Ws       = (const float*)d_in[14];
    const float* bs       = (const float*)d_in[15];
    const float* Wc       = (const float*)d_in[16];
    const float* bc       = (const float*)d_in[17];
    const float* Wt       = (const float*)d_in[18];
    const float* bt       = (const float*)d_in[19];
    const float* lnw      = (const float*)d_in[20];
    const float* lnb      = (const float*)d_in[21];
    float* out = (float*)d_out;

    float* ws    = (float*)d_ws;
    float* qbuf  = ws;             // 64x1024 (celu pre -> normed q in place)
    float* v1buf = ws + 65536;     // 64x1024
    float* attb  = ws + 131072;    // 64x1024
    float* part  = ws + 196608;    // 4 x 64x1024

    a1_qv_gemm<<<64, 256, 0, stream>>>(h_state, Wq, bq, Wv1, bv1, qbuf, v1buf);
    a2_groupnorm<<<128, 256, 0, stream>>>(qbuf, v1buf, gnw_q, gnb_q, gnw_v1, gnb_v1);
    b_attention<<<512, 256, 0, stream>>>(pat, att_mask, qbuf, v1buf,
                                         Wb, bb, Ws, bs, Wc, bc, attb);
    c1_gemm<<<128, 256, 0, stream>>>(h_state, attb, Wt, part);
    c2_ln<<<64, 256, 0, stream>>>(part, bt, lnw, lnb, out);
}

// Round 2
// 289.429 us; speedup vs baseline: 2.3391x; 2.3391x over previous
//
#include <hip/hip_runtime.h>
#include <cmath>

#define NB 64
#define NM 1024
#define NE 1024
#define NH 8
#define NHD 128
#define NMID 64
#define CELU_ALPHA 1.3f

__device__ __forceinline__ float celuf(float x) {
    return x > 0.f ? x : CELU_ALPHA * expm1f(x / CELU_ALPHA);
}

// ---------------------------------------------------------------------------
// A1: partial GEMM for qpre/v1pre, K split x4.
// grid 256 = (mat 2) x (kq 4) x (32-col chunks), block 256
// partA[mat][kq][64][1024]
// ---------------------------------------------------------------------------
__global__ __launch_bounds__(256) void a1_partial(
    const float* __restrict__ h, const float* __restrict__ Wq,
    const float* __restrict__ Wv1, float* __restrict__ partA)
{
    const int t = threadIdx.x;
    const int mat = blockIdx.x >> 7;
    const int kq = (blockIdx.x >> 5) & 3;
    const int cc = (blockIdx.x & 31) * 32;
    const int kbase = kq * 256;
    const float* __restrict__ W = mat ? Wv1 : Wq;

    __shared__ float hs[64][68];
    const int col = cc + (t & 31);
    const int rowg = t >> 5;

    float acc[8];
#pragma unroll
    for (int j = 0; j < 8; ++j) acc[j] = 0.f;

    for (int k0 = 0; k0 < 256; k0 += 64) {
        {
            const int r = t >> 2, b0 = (t & 3) * 16;
#pragma unroll
            for (int u = 0; u < 4; ++u) {
                float4 v = *(const float4*)&h[r * 1024 + kbase + k0 + b0 + 4 * u];
                *(float4*)&hs[r][b0 + 4 * u] = v;
            }
        }
        __syncthreads();
#pragma unroll 8
        for (int kl = 0; kl < 64; ++kl) {
            const float wv = W[(size_t)(kbase + k0 + kl) * 1024 + col];
#pragma unroll
            for (int j = 0; j < 8; ++j)
                acc[j] = fmaf(hs[rowg * 8 + j][kl], wv, acc[j]);
        }
        __syncthreads();
    }
    float* __restrict__ out = partA + (size_t)(mat * 4 + kq) * 65536;
#pragma unroll
    for (int j = 0; j < 8; ++j)
        out[(rowg * 8 + j) * 1024 + col] = acc[j];
}

// ---------------------------------------------------------------------------
// A2: sum partials + bias + CELU + group norm (G=8, ddof=1).
// grid 128 = (mat 2) x (row 64), block 256
// ---------------------------------------------------------------------------
__global__ __launch_bounds__(256) void a2_fused(
    const float* __restrict__ partA,
    const float* __restrict__ bq, const float* __restrict__ bv1,
    const float* __restrict__ gnw_q, const float* __restrict__ gnb_q,
    const float* __restrict__ gnw_v, const float* __restrict__ gnb_v,
    float* __restrict__ qbuf, float* __restrict__ v1buf)
{
    const int t = threadIdx.x;
    const int mat = blockIdx.x >> 6;
    const int row = blockIdx.x & 63;
    float* __restrict__ outb = mat ? v1buf : qbuf;
    const float* __restrict__ bias = mat ? bv1 : bq;
    const float* __restrict__ gw = mat ? gnw_v : gnw_q;
    const float* __restrict__ gb = mat ? gnb_v : gnb_q;

    float4 x = *(const float4*)&bias[t * 4];
#pragma unroll
    for (int kq = 0; kq < 4; ++kq) {
        const float4 p = *(const float4*)&partA[(size_t)(mat * 4 + kq) * 65536 + row * 1024 + t * 4];
        x.x += p.x; x.y += p.y; x.z += p.z; x.w += p.w;
    }
    x.x = celuf(x.x); x.y = celuf(x.y); x.z = celuf(x.z); x.w = celuf(x.w);

    float s = x.x + x.y + x.z + x.w;
#pragma unroll
    for (int m = 16; m >= 1; m >>= 1) s += __shfl_xor(s, m);
    const float mean = s * (1.f / 128.f);
    const float d0 = x.x - mean, d1 = x.y - mean, d2 = x.z - mean, d3 = x.w - mean;
    float ss = d0 * d0 + d1 * d1 + d2 * d2 + d3 * d3;
#pragma unroll
    for (int m = 16; m >= 1; m >>= 1) ss += __shfl_xor(ss, m);
    const float inv = rsqrtf(ss * (1.f / 127.f) + 1e-5f);
    const float4 w4 = *(const float4*)&gw[t * 4];
    const float4 b4 = *(const float4*)&gb[t * 4];
    float4 y;
    y.x = d0 * inv * w4.x + b4.x;
    y.y = d1 * inv * w4.y + b4.y;
    y.z = d2 * inv * w4.z + b4.z;
    y.w = d3 * inv * w4.w + b4.w;
    *(float4*)&outb[row * 1024 + t * 4] = y;
}

// ---------------------------------------------------------------------------
// B: per-(b,h) attention core. grid 512, block 256 (4 waves)
// ---------------------------------------------------------------------------
__global__ __launch_bounds__(256) void b_attention(
    const float* __restrict__ pat, const float* __restrict__ mask,
    const float* __restrict__ q, const float* __restrict__ v1,
    const float* __restrict__ Wb, const float* __restrict__ bb,
    const float* __restrict__ Ws, const float* __restrict__ bs,
    const float* __restrict__ Wc, const float* __restrict__ bc,
    float* __restrict__ att_out)
{
    const int t = threadIdx.x;
    const int b = blockIdx.x >> 3;
    const int h = blockIdx.x & 7;
    const int w = t >> 6;
    const int lane = t & 63;
    const int c = lane & 7;        // col group: cols c*8..c*8+7
    const int rg = lane >> 3;      // 0..7

    __shared__ float wbq[128][64];     // q-scaled Wb
    __shared__ float ktile[64][132];   // padded: conflict-free reads
    __shared__ float s_lds[1024];
    __shared__ float mask_lds[1024];
    __shared__ float q_lds[128];
    __shared__ float ws_lds[64];
    __shared__ float bb_lds[64];
    __shared__ float pool_red[4][64];
    __shared__ float att_red[4][128];
    __shared__ float pool2[64];
    __shared__ float red4[4];

    if (t < 128) q_lds[t] = q[b * 1024 + h * 128 + t];
    if (t >= 128 && t < 192) {
        ws_lds[t - 128] = Ws[h * 64 + (t - 128)];
        bb_lds[t - 128] = bb[h * 64 + (t - 128)];
    }
    *(float4*)&mask_lds[t * 4] = *(const float4*)&mask[b * 1024 + t * 4];
    __syncthreads();

#pragma unroll 8
    for (int u = 0; u < 32; ++u) {
        const int idx = t + 256 * u;
        wbq[idx >> 6][idx & 63] = q_lds[idx >> 6] * Wb[h * 8192 + idx];
    }

    float pool_part[8];
#pragma unroll
    for (int j = 0; j < 8; ++j) pool_part[j] = 0.f;
    const float bsh = bs[h];

    const float* __restrict__ patk = pat + (size_t)b * NM * 2048 + h * 128;

    for (int mt = 0; mt < 16; ++mt) {
        __syncthreads();
#pragma unroll
        for (int u = 0; u < 8; ++u) {
            const int idx4 = t + 256 * u;
            const int r = idx4 >> 5, iv = idx4 & 31;
            float4 v = *(const float4*)&patk[(size_t)(mt * 64 + r) * 2048 + iv * 4];
            *(float4*)&ktile[r][iv * 4] = v;
        }
        __syncthreads();

        float acc0[8], acc1[8];
#pragma unroll
        for (int j = 0; j < 8; ++j) { acc0[j] = 0.f; acc1[j] = 0.f; }

#pragma unroll 2
        for (int i4 = 0; i4 < 32; ++i4) {
            const float4 ka = *(const float4*)&ktile[w * 16 + rg][i4 * 4];
            const float4 kb = *(const float4*)&ktile[w * 16 + rg + 8][i4 * 4];
            const float kav[4] = {ka.x, ka.y, ka.z, ka.w};
            const float kbv[4] = {kb.x, kb.y, kb.z, kb.w};
#pragma unroll
            for (int di = 0; di < 4; ++di) {
                const float4 w0 = *(const float4*)&wbq[i4 * 4 + di][c * 8];
                const float4 w1 = *(const float4*)&wbq[i4 * 4 + di][c * 8 + 4];
                acc0[0] = fmaf(kav[di], w0.x, acc0[0]);
                acc0[1] = fmaf(kav[di], w0.y, acc0[1]);
                acc0[2] = fmaf(kav[di], w0.z, acc0[2]);
                acc0[3] = fmaf(kav[di], w0.w, acc0[3]);
                acc0[4] = fmaf(kav[di], w1.x, acc0[4]);
                acc0[5] = fmaf(kav[di], w1.y, acc0[5]);
                acc0[6] = fmaf(kav[di], w1.z, acc0[6]);
                acc0[7] = fmaf(kav[di], w1.w, acc0[7]);
                acc1[0] = fmaf(kbv[di], w0.x, acc1[0]);
                acc1[1] = fmaf(kbv[di], w0.y, acc1[1]);
                acc1[2] = fmaf(kbv[di], w0.z, acc1[2]);
                acc1[3] = fmaf(kbv[di], w0.w, acc1[3]);
                acc1[4] = fmaf(kbv[di], w1.x, acc1[4]);
                acc1[5] = fmaf(kbv[di], w1.y, acc1[5]);
                acc1[6] = fmaf(kbv[di], w1.z, acc1[6]);
                acc1[7] = fmaf(kbv[di], w1.w, acc1[7]);
            }
        }

        // epilogue: relu + bias, score partial, pool partial
#pragma unroll
        for (int dr = 0; dr < 2; ++dr) {
            const int m = mt * 64 + w * 16 + rg + 8 * dr;
            const float mk = mask_lds[m];
            float sp = 0.f;
#pragma unroll
            for (int j = 0; j < 8; ++j) {
                float a = (dr ? acc1[j] : acc0[j]) + bb_lds[c * 8 + j];
                a = fmaxf(a, 0.f);
                sp = fmaf(a, ws_lds[c * 8 + j], sp);
                pool_part[j] = fmaf(a, mk, pool_part[j]);
            }
            sp += __shfl_xor(sp, 1);
            sp += __shfl_xor(sp, 2);
            sp += __shfl_xor(sp, 4);
            if (c == 0) s_lds[m] = sp;
        }
    }

    // reduce pool across row-groups (rg bits = lane bits 3..5)
#pragma unroll
    for (int j = 0; j < 8; ++j) {
        float p = pool_part[j];
        p += __shfl_xor(p, 8);
        p += __shfl_xor(p, 16);
        p += __shfl_xor(p, 32);
        pool_part[j] = p;
    }
    if (lane < 8) {
#pragma unroll
        for (int j = 0; j < 8; ++j) pool_red[w][lane * 8 + j] = pool_part[j];
    }

    // mask sum
    float msp = 0.f;
#pragma unroll
    for (int u = 0; u < 4; ++u) msp += mask_lds[t + 256 * u];
#pragma unroll
    for (int m = 32; m >= 1; m >>= 1) msp += __shfl_xor(msp, m);
    if (lane == 0) red4[w] = msp;
    __syncthreads();                               // SYNC1
    const float msum = red4[0] + red4[1] + red4[2] + red4[3];

    // masked scores + max
    float sc[4];
    float mymax = -3.0e38f;
#pragma unroll
    for (int u = 0; u < 4; ++u) {
        const int m = t + 256 * u;
        const float v = (mask_lds[m] == 0.f) ? -1e9f : (s_lds[m] + bsh);
        sc[u] = v;
        mymax = fmaxf(mymax, v);
    }
#pragma unroll
    for (int m = 32; m >= 1; m >>= 1) mymax = fmaxf(mymax, __shfl_xor(mymax, m));
    __syncthreads();                               // SYNC2 (red4 reuse)
    if (lane == 0) red4[w] = mymax;
    if (t < 64)
        pool2[t] = (pool_red[0][t] + pool_red[1][t] + pool_red[2][t] + pool_red[3][t]) / msum;
    __syncthreads();                               // SYNC3
    const float gmax = fmaxf(fmaxf(red4[0], red4[1]), fmaxf(red4[2], red4[3]));
    float esp = 0.f;
#pragma unroll
    for (int u = 0; u < 4; ++u) {
        const float e = expf(sc[u] - gmax);
        s_lds[t + 256 * u] = e;
        esp += e;
    }
#pragma unroll
    for (int m = 32; m >= 1; m >>= 1) esp += __shfl_xor(esp, m);
    __syncthreads();                               // SYNC4 (red4 reuse)
    if (lane == 0) red4[w] = esp;
    __syncthreads();                               // SYNC5
    const float einv = 1.f / (red4[0] + red4[1] + red4[2] + red4[3]);
#pragma unroll
    for (int u = 0; u < 4; ++u) s_lds[t + 256 * u] *= einv;
    __syncthreads();                               // SYNC6: p ready

    // pass 2: att[d] = sum_m p[m] * v2[m,d]
    const int dg = t & 31, rwg = t >> 5;
    const float* __restrict__ patv = pat + (size_t)b * NM * 2048 + 1024 + h * 128;
    float4 a4 = {0.f, 0.f, 0.f, 0.f};
#pragma unroll 2
    for (int mt = 0; mt < 128; ++mt) {
        const int m = mt * 8 + rwg;
        const float4 v = *(const float4*)&patv[(size_t)m * 2048 + dg * 4];
        const float pw = s_lds[m];
        a4.x = fmaf(pw, v.x, a4.x);
        a4.y = fmaf(pw, v.y, a4.y);
        a4.z = fmaf(pw, v.z, a4.z);
        a4.w = fmaf(pw, v.w, a4.w);
    }
    a4.x += __shfl_xor(a4.x, 32);
    a4.y += __shfl_xor(a4.y, 32);
    a4.z += __shfl_xor(a4.z, 32);
    a4.w += __shfl_xor(a4.w, 32);
    if (lane < 32) *(float4*)&att_red[w][dg * 4] = a4;
    __syncthreads();

    if (t < 128) {
        const int d = t;
        const float attv = att_red[0][d] + att_red[1][d] + att_red[2][d] + att_red[3][d];
        float ac = bc[h * 128 + d];
#pragma unroll 8
        for (int o = 0; o < 64; ++o)
            ac = fmaf(pool2[o], Wc[h * 8192 + o * 128 + d], ac);
        const float sig = 1.f / (1.f + expf(-ac));
        att_out[b * 1024 + h * 128 + d] = attv * v1[b * 1024 + h * 128 + d] * sig;
    }
}

// ---------------------------------------------------------------------------
// C1: partial[kq] = x_kq @ Wt_kq  (K split in 8, 256 each).
// grid 256 = (kq 8) x (32-col chunks), block 256
// ---------------------------------------------------------------------------
__global__ __launch_bounds__(256) void c1_partial(
    const float* __restrict__ h, const float* __restrict__ att,
    const float* __restrict__ Wt, float* __restrict__ part)
{
    const int t = threadIdx.x;
    const int kq = blockIdx.x >> 5;
    const int cc = (blockIdx.x & 31) * 32;
    const int col = cc + (t & 31);
    const int rowg = t >> 5;
    const float* __restrict__ x = (kq < 4) ? h : att;
    const int kbase = (kq & 3) * 256;

    __shared__ float xs[64][68];
    float acc[8];
#pragma unroll
    for (int j = 0; j < 8; ++j) acc[j] = 0.f;

    for (int k0 = 0; k0 < 256; k0 += 64) {
        {
            const int r = t >> 2, b0 = (t & 3) * 16;
#pragma unroll
            for (int u = 0; u < 4; ++u) {
                float4 v = *(const float4*)&x[r * 1024 + kbase + k0 + b0 + 4 * u];
                *(float4*)&xs[r][b0 + 4 * u] = v;
            }
        }
        __syncthreads();
#pragma unroll 8
        for (int kl = 0; kl < 64; ++kl) {
            const float wv = Wt[(size_t)(kq * 256 + k0 + kl) * 1024 + col];
#pragma unroll
            for (int j = 0; j < 8; ++j)
                acc[j] = fmaf(xs[rowg * 8 + j][kl], wv, acc[j]);
        }
        __syncthreads();
    }
#pragma unroll
    for (int j = 0; j < 8; ++j)
        part[(size_t)kq * 65536 + (rowg * 8 + j) * 1024 + col] = acc[j];
}

// ---------------------------------------------------------------------------
// C2: sum 8 partials + bt, LayerNorm (ddof=0). grid 64 rows, block 256
// ---------------------------------------------------------------------------
__global__ __launch_bounds__(256) void c2_ln(
    const float* __restrict__ part, const float* __restrict__ bt,
    const float* __restrict__ lnw, const float* __restrict__ lnb,
    float* __restrict__ out)
{
    const int t = threadIdx.x;
    const int row = blockIdx.x;
    const int w = t >> 6, lane = t & 63;
    __shared__ float red[4];

    float4 v = *(const float4*)&bt[t * 4];
#pragma unroll
    for (int qd = 0; qd < 8; ++qd) {
        const float4 p = *(const float4*)&part[(size_t)qd * 65536 + row * 1024 + t * 4];
        v.x += p.x; v.y += p.y; v.z += p.z; v.w += p.w;
    }
    float s = v.x + v.y + v.z + v.w;
#pragma unroll
    for (int m = 32; m >= 1; m >>= 1) s += __shfl_xor(s, m);
    if (lane == 0) red[w] = s;
    __syncthreads();
    const float mean = (red[0] + red[1] + red[2] + red[3]) * (1.f / 1024.f);
    __syncthreads();
    const float d0 = v.x - mean, d1 = v.y - mean, d2 = v.z - mean, d3 = v.w - mean;
    float ss = d0 * d0 + d1 * d1 + d2 * d2 + d3 * d3;
#pragma unroll
    for (int m = 32; m >= 1; m >>= 1) ss += __shfl_xor(ss, m);
    if (lane == 0) red[w] = ss;
    __syncthreads();
    const float var = (red[0] + red[1] + red[2] + red[3]) * (1.f / 1024.f);
    const float inv = rsqrtf(var + 1e-5f);
    const float4 w4 = *(const float4*)&lnw[t * 4];
    const float4 b4 = *(const float4*)&lnb[t * 4];
    float4 y;
    y.x = d0 * inv * w4.x + b4.x;
    y.y = d1 * inv * w4.y + b4.y;
    y.z = d2 * inv * w4.z + b4.z;
    y.w = d3 * inv * w4.w + b4.w;
    *(float4*)&out[row * 1024 + t * 4] = y;
}

// ---------------------------------------------------------------------------
extern "C" void kernel_launch(void* const* d_in, const int* in_sizes, int n_in,
                              void* d_out, int out_size, void* d_ws, size_t ws_size,
                              hipStream_t stream)
{
    const float* h_state  = (const float*)d_in[0];
    // d_in[1] = att_feats: UNUSED by the reference — never read (saves 256 MB)
    const float* att_mask = (const float*)d_in[2];
    const float* pat      = (const float*)d_in[3];
    const float* Wq       = (const float*)d_in[4];
    const float* bq       = (const float*)d_in[5];
    const float* gnw_q    = (const float*)d_in[6];
    const float* gnb_q    = (const float*)d_in[7];
    const float* Wv1      = (const float*)d_in[8];
    const float* bv1      = (const float*)d_in[9];
    const float* gnw_v1   = (const float*)d_in[10];
    const float* gnb_v1   = (const float*)d_in[11];
    const float* Wb       = (const float*)d_in[12];
    const float* bb       = (const float*)d_in[13];
    const float* Ws       = (const float*)d_in[14];
    const float* bs       = (const float*)d_in[15];
    const float* Wc       = (const float*)d_in[16];
    const float* bc       = (const float*)d_in[17];
    const float* Wt       = (const float*)d_in[18];
    const float* bt       = (const float*)d_in[19];
    const float* lnw      = (const float*)d_in[20];
    const float* lnb      = (const float*)d_in[21];
    float* out = (float*)d_out;

    float* ws    = (float*)d_ws;
    float* qbuf  = ws;             // 64x1024
    float* v1buf = ws + 65536;     // 64x1024
    float* attb  = ws + 131072;    // 64x1024
    float* parts = ws + 196608;    // 8 x 64x1024 (A1 partials, then reused for C1)

    a1_partial<<<256, 256, 0, stream>>>(h_state, Wq, Wv1, parts);
    a2_fused<<<128, 256, 0, stream>>>(parts, bq, bv1, gnw_q, gnb_q, gnw_v1, gnb_v1,
                                      qbuf, v1buf);
    b_attention<<<512, 256, 0, stream>>>(pat, att_mask, qbuf, v1buf,
                                         Wb, bb, Ws, bs, Wc, bc, attb);
    c1_partial<<<256, 256, 0, stream>>>(h_state, attb, Wt, parts);
    c2_ln<<<64, 256, 0, stream>>>(parts, bt, lnw, lnb, out);
}

// Round 3
// 232.690 us; speedup vs baseline: 2.9095x; 1.2438x over previous
//
#include <hip/hip_runtime.h>
#include <hip/hip_bf16.h>
#include <cmath>

#define NB 64
#define NM 1024
#define NE 1024
#define NH 8
#define NHD 128
#define NMID 64
#define CELU_ALPHA 1.3f

typedef __attribute__((ext_vector_type(8))) short bf16x8;
typedef __attribute__((ext_vector_type(4))) float f32x4;

__device__ __forceinline__ float celuf(float x) {
    return x > 0.f ? x : CELU_ALPHA * expm1f(x / CELU_ALPHA);
}

__device__ __forceinline__ short f2bf(float x) {
    __hip_bfloat16 b = __float2bfloat16(x);
    return *reinterpret_cast<short*>(&b);
}

// ---------------------------------------------------------------------------
// A1: partial GEMM for qpre/v1pre, K split x4.
// grid 256 = (mat 2) x (kq 4) x (32-col chunks), block 256
// ---------------------------------------------------------------------------
__global__ __launch_bounds__(256) void a1_partial(
    const float* __restrict__ h, const float* __restrict__ Wq,
    const float* __restrict__ Wv1, float* __restrict__ partA)
{
    const int t = threadIdx.x;
    const int mat = blockIdx.x >> 7;
    const int kq = (blockIdx.x >> 5) & 3;
    const int cc = (blockIdx.x & 31) * 32;
    const int kbase = kq * 256;
    const float* __restrict__ W = mat ? Wv1 : Wq;

    __shared__ float hs[64][68];
    const int col = cc + (t & 31);
    const int rowg = t >> 5;

    float acc[8];
#pragma unroll
    for (int j = 0; j < 8; ++j) acc[j] = 0.f;

    for (int k0 = 0; k0 < 256; k0 += 64) {
        {
            const int r = t >> 2, b0 = (t & 3) * 16;
#pragma unroll
            for (int u = 0; u < 4; ++u) {
                float4 v = *(const float4*)&h[r * 1024 + kbase + k0 + b0 + 4 * u];
                *(float4*)&hs[r][b0 + 4 * u] = v;
            }
        }
        __syncthreads();
#pragma unroll 8
        for (int kl = 0; kl < 64; ++kl) {
            const float wv = W[(size_t)(kbase + k0 + kl) * 1024 + col];
#pragma unroll
            for (int j = 0; j < 8; ++j)
                acc[j] = fmaf(hs[rowg * 8 + j][kl], wv, acc[j]);
        }
        __syncthreads();
    }
    float* __restrict__ out = partA + (size_t)(mat * 4 + kq) * 65536;
#pragma unroll
    for (int j = 0; j < 8; ++j)
        out[(rowg * 8 + j) * 1024 + col] = acc[j];
}

// ---------------------------------------------------------------------------
// A2: sum partials + bias + CELU + group norm (G=8, ddof=1).
// ---------------------------------------------------------------------------
__global__ __launch_bounds__(256) void a2_fused(
    const float* __restrict__ partA,
    const float* __restrict__ bq, const float* __restrict__ bv1,
    const float* __restrict__ gnw_q, const float* __restrict__ gnb_q,
    const float* __restrict__ gnw_v, const float* __restrict__ gnb_v,
    float* __restrict__ qbuf, float* __restrict__ v1buf)
{
    const int t = threadIdx.x;
    const int mat = blockIdx.x >> 6;
    const int row = blockIdx.x & 63;
    float* __restrict__ outb = mat ? v1buf : qbuf;
    const float* __restrict__ bias = mat ? bv1 : bq;
    const float* __restrict__ gw = mat ? gnw_v : gnw_q;
    const float* __restrict__ gb = mat ? gnb_v : gnb_q;

    float4 x = *(const float4*)&bias[t * 4];
#pragma unroll
    for (int kq = 0; kq < 4; ++kq) {
        const float4 p = *(const float4*)&partA[(size_t)(mat * 4 + kq) * 65536 + row * 1024 + t * 4];
        x.x += p.x; x.y += p.y; x.z += p.z; x.w += p.w;
    }
    x.x = celuf(x.x); x.y = celuf(x.y); x.z = celuf(x.z); x.w = celuf(x.w);

    float s = x.x + x.y + x.z + x.w;
#pragma unroll
    for (int m = 16; m >= 1; m >>= 1) s += __shfl_xor(s, m);
    const float mean = s * (1.f / 128.f);
    const float d0 = x.x - mean, d1 = x.y - mean, d2 = x.z - mean, d3 = x.w - mean;
    float ss = d0 * d0 + d1 * d1 + d2 * d2 + d3 * d3;
#pragma unroll
    for (int m = 16; m >= 1; m >>= 1) ss += __shfl_xor(ss, m);
    const float inv = rsqrtf(ss * (1.f / 127.f) + 1e-5f);
    const float4 w4 = *(const float4*)&gw[t * 4];
    const float4 b4 = *(const float4*)&gb[t * 4];
    float4 y;
    y.x = d0 * inv * w4.x + b4.x;
    y.y = d1 * inv * w4.y + b4.y;
    y.z = d2 * inv * w4.z + b4.z;
    y.w = d3 * inv * w4.w + b4.w;
    *(float4*)&outb[row * 1024 + t * 4] = y;
}

// ---------------------------------------------------------------------------
// B: per-(b,h) attention core, MFMA pass-1. grid 512, block 256 (4 waves)
//
// pass1: am = relu(K(1024x128) @ wbq(128x64) + bb) via mfma_f32_16x16x32_bf16.
//   A-frags loaded DIRECTLY from global (fp32 -> bf16 in reg), no LDS staging.
//   B-frags (wbqT) built once in LDS, then held in 64 VGPRs.
//   Layouts (guide §3): A row=l&15, k=(l>>4)*8+j ; B col=l&15, k=(l>>4)*8+j ;
//                       D col=l&15, row=(l>>4)*4+j.
// ---------------------------------------------------------------------------
__global__ __launch_bounds__(256, 2) void b_attention(
    const float* __restrict__ pat, const float* __restrict__ mask,
    const float* __restrict__ q, const float* __restrict__ v1,
    const float* __restrict__ Wb, const float* __restrict__ bb,
    const float* __restrict__ Ws, const float* __restrict__ bs,
    const float* __restrict__ Wc, const float* __restrict__ bc,
    float* __restrict__ att_out)
{
    const int t = threadIdx.x;
    const int b = blockIdx.x >> 3;
    const int h = blockIdx.x & 7;
    const int w = t >> 6;
    const int lane = t & 63;
    const int ln15 = lane & 15;
    const int lg = lane >> 4;          // 0..3

    __shared__ short wbqT[64 * 136];   // [o][i] bf16, stride 136 (16B-aligned rows)
    __shared__ float s_lds[1024];
    __shared__ float mask_lds[1024];
    __shared__ float q_lds[128];
    __shared__ float pool_red[4][64];
    __shared__ float att_red[4][128];
    __shared__ float pool2[64];
    __shared__ float red4[4];

    if (t < 128) q_lds[t] = q[b * 1024 + h * 128 + t];
    *(float4*)&mask_lds[t * 4] = *(const float4*)&mask[b * 1024 + t * 4];
    __syncthreads();

    // build wbqT[o][i] = bf16(q[i] * Wb[h][i][o])  (one-time, 8192 elems)
    {
        const int o = t >> 2;
        const int i0 = (t & 3) * 32;
#pragma unroll 8
        for (int u = 0; u < 32; ++u) {
            const int i = i0 + u;
            wbqT[o * 136 + i] = f2bf(q_lds[i] * Wb[h * 8192 + i * 64 + o]);
        }
    }
    __syncthreads();

    // B-frags to registers: bfr[nt][ks] covers cols nt*16+ln15, k = ks*32+lg*8..+7
    bf16x8 bfr[4][4];
#pragma unroll
    for (int nt = 0; nt < 4; ++nt)
#pragma unroll
        for (int ks = 0; ks < 4; ++ks)
            bfr[nt][ks] = *(const bf16x8*)&wbqT[(nt * 16 + ln15) * 136 + ks * 32 + lg * 8];

    float wsr[4], bbr[4];
#pragma unroll
    for (int nt = 0; nt < 4; ++nt) {
        wsr[nt] = Ws[h * 64 + nt * 16 + ln15];
        bbr[nt] = bb[h * 64 + nt * 16 + ln15];
    }
    const float bsh = bs[h];
    float pool_part[4] = {0.f, 0.f, 0.f, 0.f};

    const float* __restrict__ patk = pat + (size_t)b * NM * 2048 + h * 128;

    // pass 1: wave w owns rows [w*256, w*256+256) as 16 M-tiles of 16 rows
    for (int it = 0; it < 16; ++it) {
        const int m0 = (w * 16 + it) * 16;
        const float* __restrict__ rowp = patk + (size_t)(m0 + ln15) * 2048 + lg * 8;

        bf16x8 af[4];
#pragma unroll
        for (int ks = 0; ks < 4; ++ks) {
            const float4 x = *(const float4*)(rowp + ks * 32);
            const float4 y = *(const float4*)(rowp + ks * 32 + 4);
            union { bf16x8 v; short s[8]; } u8;
            u8.s[0] = f2bf(x.x); u8.s[1] = f2bf(x.y);
            u8.s[2] = f2bf(x.z); u8.s[3] = f2bf(x.w);
            u8.s[4] = f2bf(y.x); u8.s[5] = f2bf(y.y);
            u8.s[6] = f2bf(y.z); u8.s[7] = f2bf(y.w);
            af[ks] = u8.v;
        }

        f32x4 acc[4];
#pragma unroll
        for (int nt = 0; nt < 4; ++nt) acc[nt] = (f32x4){0.f, 0.f, 0.f, 0.f};
#pragma unroll
        for (int ks = 0; ks < 4; ++ks)
#pragma unroll
            for (int nt = 0; nt < 4; ++nt)
                acc[nt] = __builtin_amdgcn_mfma_f32_16x16x32_bf16(af[ks], bfr[nt][ks], acc[nt], 0, 0, 0);

        // epilogue: bias+relu, score partial (dot with Ws), pool partial
#pragma unroll
        for (int j = 0; j < 4; ++j) {
            const int m = m0 + lg * 4 + j;
            const float mk = mask_lds[m];
            float sp = 0.f;
#pragma unroll
            for (int nt = 0; nt < 4; ++nt) {
                float a = acc[nt][j] + bbr[nt];
                a = fmaxf(a, 0.f);
                sp = fmaf(a, wsr[nt], sp);
                pool_part[nt] = fmaf(a, mk, pool_part[nt]);
            }
            sp += __shfl_xor(sp, 1);
            sp += __shfl_xor(sp, 2);
            sp += __shfl_xor(sp, 4);
            sp += __shfl_xor(sp, 8);
            if (ln15 == 0) s_lds[m] = sp;
        }
    }

    // pool: reduce over lane groups (bits 4,5), cols o = nt*16 + ln15
#pragma unroll
    for (int nt = 0; nt < 4; ++nt) {
        float p = pool_part[nt];
        p += __shfl_xor(p, 16);
        p += __shfl_xor(p, 32);
        if (lane < 16) pool_red[w][nt * 16 + lane] = p;
    }

    // mask sum
    float msp = 0.f;
#pragma unroll
    for (int u = 0; u < 4; ++u) msp += mask_lds[t + 256 * u];
#pragma unroll
    for (int m = 32; m >= 1; m >>= 1) msp += __shfl_xor(msp, m);
    if (lane == 0) red4[w] = msp;
    __syncthreads();                               // SYNC1
    const float msum = red4[0] + red4[1] + red4[2] + red4[3];

    // masked scores + max
    float sc[4];
    float mymax = -3.0e38f;
#pragma unroll
    for (int u = 0; u < 4; ++u) {
        const int m = t + 256 * u;
        const float v = (mask_lds[m] == 0.f) ? -1e9f : (s_lds[m] + bsh);
        sc[u] = v;
        mymax = fmaxf(mymax, v);
    }
#pragma unroll
    for (int m = 32; m >= 1; m >>= 1) mymax = fmaxf(mymax, __shfl_xor(mymax, m));
    __syncthreads();                               // SYNC2
    if (lane == 0) red4[w] = mymax;
    if (t < 64)
        pool2[t] = (pool_red[0][t] + pool_red[1][t] + pool_red[2][t] + pool_red[3][t]) / msum;
    __syncthreads();                               // SYNC3
    const float gmax = fmaxf(fmaxf(red4[0], red4[1]), fmaxf(red4[2], red4[3]));
    float esp = 0.f;
#pragma unroll
    for (int u = 0; u < 4; ++u) {
        const float e = expf(sc[u] - gmax);
        s_lds[t + 256 * u] = e;
        esp += e;
    }
#pragma unroll
    for (int m = 32; m >= 1; m >>= 1) esp += __shfl_xor(esp, m);
    __syncthreads();                               // SYNC4
    if (lane == 0) red4[w] = esp;
    __syncthreads();                               // SYNC5
    const float einv = 1.f / (red4[0] + red4[1] + red4[2] + red4[3]);
#pragma unroll
    for (int u = 0; u < 4; ++u) s_lds[t + 256 * u] *= einv;
    __syncthreads();                               // SYNC6: p ready

    // pass 2: att[d] = sum_m p[m] * v2[m,d]
    const int dg = t & 31, rwg = t >> 5;
    const float* __restrict__ patv = pat + (size_t)b * NM * 2048 + 1024 + h * 128;
    float4 a4 = {0.f, 0.f, 0.f, 0.f};
#pragma unroll 2
    for (int mt = 0; mt < 128; ++mt) {
        const int m = mt * 8 + rwg;
        const float4 v = *(const float4*)&patv[(size_t)m * 2048 + dg * 4];
        const float pw = s_lds[m];
        a4.x = fmaf(pw, v.x, a4.x);
        a4.y = fmaf(pw, v.y, a4.y);
        a4.z = fmaf(pw, v.z, a4.z);
        a4.w = fmaf(pw, v.w, a4.w);
    }
    a4.x += __shfl_xor(a4.x, 32);
    a4.y += __shfl_xor(a4.y, 32);
    a4.z += __shfl_xor(a4.z, 32);
    a4.w += __shfl_xor(a4.w, 32);
    if (lane < 32) *(float4*)&att_red[w][dg * 4] = a4;
    __syncthreads();

    if (t < 128) {
        const int d = t;
        const float attv = att_red[0][d] + att_red[1][d] + att_red[2][d] + att_red[3][d];
        float ac = bc[h * 128 + d];
#pragma unroll 8
        for (int o = 0; o < 64; ++o)
            ac = fmaf(pool2[o], Wc[h * 8192 + o * 128 + d], ac);
        const float sig = 1.f / (1.f + expf(-ac));
        att_out[b * 1024 + h * 128 + d] = attv * v1[b * 1024 + h * 128 + d] * sig;
    }
}

// ---------------------------------------------------------------------------
// C1: partial[kq] = x_kq @ Wt_kq  (K split in 8, 256 each).
// ---------------------------------------------------------------------------
__global__ __launch_bounds__(256) void c1_partial(
    const float* __restrict__ h, const float* __restrict__ att,
    const float* __restrict__ Wt, float* __restrict__ part)
{
    const int t = threadIdx.x;
    const int kq = blockIdx.x >> 5;
    const int cc = (blockIdx.x & 31) * 32;
    const int col = cc + (t & 31);
    const int rowg = t >> 5;
    const float* __restrict__ x = (kq < 4) ? h : att;
    const int kbase = (kq & 3) * 256;

    __shared__ float xs[64][68];
    float acc[8];
#pragma unroll
    for (int j = 0; j < 8; ++j) acc[j] = 0.f;

    for (int k0 = 0; k0 < 256; k0 += 64) {
        {
            const int r = t >> 2, b0 = (t & 3) * 16;
#pragma unroll
            for (int u = 0; u < 4; ++u) {
                float4 v = *(const float4*)&x[r * 1024 + kbase + k0 + b0 + 4 * u];
                *(float4*)&xs[r][b0 + 4 * u] = v;
            }
        }
        __syncthreads();
#pragma unroll 8
        for (int kl = 0; kl < 64; ++kl) {
            const float wv = Wt[(size_t)(kq * 256 + k0 + kl) * 1024 + col];
#pragma unroll
            for (int j = 0; j < 8; ++j)
                acc[j] = fmaf(xs[rowg * 8 + j][kl], wv, acc[j]);
        }
        __syncthreads();
    }
#pragma unroll
    for (int j = 0; j < 8; ++j)
        part[(size_t)kq * 65536 + (rowg * 8 + j) * 1024 + col] = acc[j];
}

// ---------------------------------------------------------------------------
// C2: sum 8 partials + bt, LayerNorm (ddof=0). grid 64 rows, block 256
// ---------------------------------------------------------------------------
__global__ __launch_bounds__(256) void c2_ln(
    const float* __restrict__ part, const float* __restrict__ bt,
    const float* __restrict__ lnw, const float* __restrict__ lnb,
    float* __restrict__ out)
{
    const int t = threadIdx.x;
    const int row = blockIdx.x;
    const int w = t >> 6, lane = t & 63;
    __shared__ float red[4];

    float4 v = *(const float4*)&bt[t * 4];
#pragma unroll
    for (int qd = 0; qd < 8; ++qd) {
        const float4 p = *(const float4*)&part[(size_t)qd * 65536 + row * 1024 + t * 4];
        v.x += p.x; v.y += p.y; v.z += p.z; v.w += p.w;
    }
    float s = v.x + v.y + v.z + v.w;
#pragma unroll
    for (int m = 32; m >= 1; m >>= 1) s += __shfl_xor(s, m);
    if (lane == 0) red[w] = s;
    __syncthreads();
    const float mean = (red[0] + red[1] + red[2] + red[3]) * (1.f / 1024.f);
    __syncthreads();
    const float d0 = v.x - mean, d1 = v.y - mean, d2 = v.z - mean, d3 = v.w - mean;
    float ss = d0 * d0 + d1 * d1 + d2 * d2 + d3 * d3;
#pragma unroll
    for (int m = 32; m >= 1; m >>= 1) ss += __shfl_xor(ss, m);
    if (lane == 0) red[w] = ss;
    __syncthreads();
    const float var = (red[0] + red[1] + red[2] + red[3]) * (1.f / 1024.f);
    const float inv = rsqrtf(var + 1e-5f);
    const float4 w4 = *(const float4*)&lnw[t * 4];
    const float4 b4 = *(const float4*)&lnb[t * 4];
    float4 y;
    y.x = d0 * inv * w4.x + b4.x;
    y.y = d1 * inv * w4.y + b4.y;
    y.z = d2 * inv * w4.z + b4.z;
    y.w = d3 * inv * w4.w + b4.w;
    *(float4*)&out[row * 1024 + t * 4] = y;
}

// ---------------------------------------------------------------------------
extern "C" void kernel_launch(void* const* d_in, const int* in_sizes, int n_in,
                              void* d_out, int out_size, void* d_ws, size_t ws_size,
                              hipStream_t stream)
{
    const float* h_state  = (const float*)d_in[0];
    // d_in[1] = att_feats: UNUSED by the reference — never read (saves 256 MB)
    const float* att_mask = (const float*)d_in[2];
    const float* pat      = (const float*)d_in[3];
    const float* Wq       = (const float*)d_in[4];
    const float* bq       = (const float*)d_in[5];
    const float* gnw_q    = (const float*)d_in[6];
    const float* gnb_q    = (const float*)d_in[7];
    const float* Wv1      = (const float*)d_in[8];
    const float* bv1      = (const float*)d_in[9];
    const float* gnw_v1   = (const float*)d_in[10];
    const float* gnb_v1   = (const float*)d_in[11];
    const float* Wb       = (const float*)d_in[12];
    const float* bb       = (const float*)d_in[13];
    const float* Ws       = (const float*)d_in[14];
    const float* bs       = (const float*)d_in[15];
    const float* Wc       = (const float*)d_in[16];
    const float* bc       = (const float*)d_in[17];
    const float* Wt       = (const float*)d_in[18];
    const float* bt       = (const float*)d_in[19];
    const float* lnw      = (const float*)d_in[20];
    const float* lnb      = (const float*)d_in[21];
    float* out = (float*)d_out;

    float* ws    = (float*)d_ws;
    float* qbuf  = ws;             // 64x1024
    float* v1buf = ws + 65536;     // 64x1024
    float* attb  = ws + 131072;    // 64x1024
    float* parts = ws + 196608;    // 8 x 64x1024 (A1 partials, then reused for C1)

    a1_partial<<<256, 256, 0, stream>>>(h_state, Wq, Wv1, parts);
    a2_fused<<<128, 256, 0, stream>>>(parts, bq, bv1, gnw_q, gnb_q, gnw_v1, gnb_v1,
                                      qbuf, v1buf);
    b_attention<<<512, 256, 0, stream>>>(pat, att_mask, qbuf, v1buf,
                                         Wb, bb, Ws, bs, Wc, bc, attb);
    c1_partial<<<256, 256, 0, stream>>>(h_state, attb, Wt, parts);
    c2_ln<<<64, 256, 0, stream>>>(parts, bt, lnw, lnb, out);
}

// Round 4
// 206.565 us; speedup vs baseline: 3.2775x; 1.1265x over previous
//
#include <hip/hip_runtime.h>
#include <hip/hip_bf16.h>
#include <cmath>

#define NB 64
#define NM 1024
#define NE 1024
#define NH 8
#define NHD 128
#define NMID 64
#define CELU_ALPHA 1.3f

typedef __attribute__((ext_vector_type(8))) short bf16x8;
typedef __attribute__((ext_vector_type(4))) float f32x4;

__device__ __forceinline__ float celuf(float x) {
    return x > 0.f ? x : CELU_ALPHA * expm1f(x / CELU_ALPHA);
}

__device__ __forceinline__ short f2bf(float x) {
    __hip_bfloat16 b = __float2bfloat16(x);
    return *reinterpret_cast<short*>(&b);
}

// ---------------------------------------------------------------------------
// A1: partial GEMM for qpre/v1pre, K split x8.
// grid 512 = (mat 2) x (kq 8) x (32-col chunks), block 256
// ---------------------------------------------------------------------------
__global__ __launch_bounds__(256) void a1_partial(
    const float* __restrict__ h, const float* __restrict__ Wq,
    const float* __restrict__ Wv1, float* __restrict__ partA)
{
    const int t = threadIdx.x;
    const int mat = blockIdx.x >> 8;
    const int kq = (blockIdx.x >> 5) & 7;
    const int cc = (blockIdx.x & 31) * 32;
    const int kbase = kq * 128;
    const float* __restrict__ W = mat ? Wv1 : Wq;

    __shared__ float hs[64][68];
    const int col = cc + (t & 31);
    const int rowg = t >> 5;

    float acc[8];
#pragma unroll
    for (int j = 0; j < 8; ++j) acc[j] = 0.f;

    for (int k0 = 0; k0 < 128; k0 += 64) {
        {
            const int r = t >> 2, b0 = (t & 3) * 16;
#pragma unroll
            for (int u = 0; u < 4; ++u) {
                float4 v = *(const float4*)&h[r * 1024 + kbase + k0 + b0 + 4 * u];
                *(float4*)&hs[r][b0 + 4 * u] = v;
            }
        }
        __syncthreads();
#pragma unroll 8
        for (int kl = 0; kl < 64; ++kl) {
            const float wv = W[(size_t)(kbase + k0 + kl) * 1024 + col];
#pragma unroll
            for (int j = 0; j < 8; ++j)
                acc[j] = fmaf(hs[rowg * 8 + j][kl], wv, acc[j]);
        }
        __syncthreads();
    }
    float* __restrict__ out = partA + (size_t)(mat * 8 + kq) * 65536;
#pragma unroll
    for (int j = 0; j < 8; ++j)
        out[(rowg * 8 + j) * 1024 + col] = acc[j];
}

// ---------------------------------------------------------------------------
// A2: sum 8 partials + bias + CELU + group norm (G=8, ddof=1).
// grid 128 = (mat 2) x (row 64)
// ---------------------------------------------------------------------------
__global__ __launch_bounds__(256) void a2_fused(
    const float* __restrict__ partA,
    const float* __restrict__ bq, const float* __restrict__ bv1,
    const float* __restrict__ gnw_q, const float* __restrict__ gnb_q,
    const float* __restrict__ gnw_v, const float* __restrict__ gnb_v,
    float* __restrict__ qbuf, float* __restrict__ v1buf)
{
    const int t = threadIdx.x;
    const int mat = blockIdx.x >> 6;
    const int row = blockIdx.x & 63;
    float* __restrict__ outb = mat ? v1buf : qbuf;
    const float* __restrict__ bias = mat ? bv1 : bq;
    const float* __restrict__ gw = mat ? gnw_v : gnw_q;
    const float* __restrict__ gb = mat ? gnb_v : gnb_q;

    float4 x = *(const float4*)&bias[t * 4];
#pragma unroll
    for (int kq = 0; kq < 8; ++kq) {
        const float4 p = *(const float4*)&partA[(size_t)(mat * 8 + kq) * 65536 + row * 1024 + t * 4];
        x.x += p.x; x.y += p.y; x.z += p.z; x.w += p.w;
    }
    x.x = celuf(x.x); x.y = celuf(x.y); x.z = celuf(x.z); x.w = celuf(x.w);

    float s = x.x + x.y + x.z + x.w;
#pragma unroll
    for (int m = 16; m >= 1; m >>= 1) s += __shfl_xor(s, m);
    const float mean = s * (1.f / 128.f);
    const float d0 = x.x - mean, d1 = x.y - mean, d2 = x.z - mean, d3 = x.w - mean;
    float ss = d0 * d0 + d1 * d1 + d2 * d2 + d3 * d3;
#pragma unroll
    for (int m = 16; m >= 1; m >>= 1) ss += __shfl_xor(ss, m);
    const float inv = rsqrtf(ss * (1.f / 127.f) + 1e-5f);
    const float4 w4 = *(const float4*)&gw[t * 4];
    const float4 b4 = *(const float4*)&gb[t * 4];
    float4 y;
    y.x = d0 * inv * w4.x + b4.x;
    y.y = d1 * inv * w4.y + b4.y;
    y.z = d2 * inv * w4.z + b4.z;
    y.w = d3 * inv * w4.w + b4.w;
    *(float4*)&outb[row * 1024 + t * 4] = y;
}

// ---------------------------------------------------------------------------
// B1: scores + pool partials over a 256-row chunk. grid 2048 = (b,h,chunk)
// score[bh][m] = relu(K wbq + bb) . Ws + bs ;  pool_pt[bid][o] partial
// ---------------------------------------------------------------------------
__global__ __launch_bounds__(256) void b1_scores(
    const float* __restrict__ pat, const float* __restrict__ mask,
    const float* __restrict__ q,
    const float* __restrict__ Wb, const float* __restrict__ bb,
    const float* __restrict__ Ws, const float* __restrict__ bs,
    float* __restrict__ score, float* __restrict__ pool_pt)
{
    const int t = threadIdx.x;
    const int bid = blockIdx.x;
    const int b = bid >> 5;
    const int h = (bid >> 2) & 7;
    const int chunk = bid & 3;
    const int w = t >> 6;
    const int lane = t & 63;
    const int ln15 = lane & 15;
    const int lg = lane >> 4;

    __shared__ short wbqT[64 * 136];
    __shared__ float q_lds[128];
    __shared__ float mask_lds[256];
    __shared__ float pool_red[4][64];

    if (t < 128) q_lds[t] = q[b * 1024 + h * 128 + t];
    if (t >= 128) mask_lds[t - 128] = mask[b * 1024 + chunk * 256 + (t - 128)];
    if (t < 128) mask_lds[128 + t] = mask[b * 1024 + chunk * 256 + 128 + t];
    // oops ordering: rewrite cleanly below (both halves covered):
    __syncthreads();
    if (t < 256) mask_lds[t] = mask[b * 1024 + chunk * 256 + t];
    __syncthreads();

    {
        const int o = t >> 2;
        const int i0 = (t & 3) * 32;
#pragma unroll 8
        for (int u = 0; u < 32; ++u) {
            const int i = i0 + u;
            wbqT[o * 136 + i] = f2bf(q_lds[i] * Wb[h * 8192 + i * 64 + o]);
        }
    }
    __syncthreads();

    bf16x8 bfr[4][4];
#pragma unroll
    for (int nt = 0; nt < 4; ++nt)
#pragma unroll
        for (int ks = 0; ks < 4; ++ks)
            bfr[nt][ks] = *(const bf16x8*)&wbqT[(nt * 16 + ln15) * 136 + ks * 32 + lg * 8];

    float wsr[4], bbr[4];
#pragma unroll
    for (int nt = 0; nt < 4; ++nt) {
        wsr[nt] = Ws[h * 64 + nt * 16 + ln15];
        bbr[nt] = bb[h * 64 + nt * 16 + ln15];
    }
    const float bsh = bs[h];
    float pool_part[4] = {0.f, 0.f, 0.f, 0.f};

    const float* __restrict__ patk = pat + (size_t)b * NM * 2048 + h * 128;
    float* __restrict__ srow = score + (size_t)(bid >> 2) * 1024 + chunk * 256;

    for (int it = 0; it < 4; ++it) {
        const int ml0 = (w * 4 + it) * 16;                 // row within chunk
        const int m0 = chunk * 256 + ml0;                  // global row
        const float* __restrict__ rowp = patk + (size_t)(m0 + ln15) * 2048 + lg * 8;

        bf16x8 af[4];
#pragma unroll
        for (int ks = 0; ks < 4; ++ks) {
            const float4 x = *(const float4*)(rowp + ks * 32);
            const float4 y = *(const float4*)(rowp + ks * 32 + 4);
            union { bf16x8 v; short s[8]; } u8;
            u8.s[0] = f2bf(x.x); u8.s[1] = f2bf(x.y);
            u8.s[2] = f2bf(x.z); u8.s[3] = f2bf(x.w);
            u8.s[4] = f2bf(y.x); u8.s[5] = f2bf(y.y);
            u8.s[6] = f2bf(y.z); u8.s[7] = f2bf(y.w);
            af[ks] = u8.v;
        }

        f32x4 acc[4];
#pragma unroll
        for (int nt = 0; nt < 4; ++nt) acc[nt] = (f32x4){0.f, 0.f, 0.f, 0.f};
#pragma unroll
        for (int ks = 0; ks < 4; ++ks)
#pragma unroll
            for (int nt = 0; nt < 4; ++nt)
                acc[nt] = __builtin_amdgcn_mfma_f32_16x16x32_bf16(af[ks], bfr[nt][ks], acc[nt], 0, 0, 0);

#pragma unroll
        for (int j = 0; j < 4; ++j) {
            const int ml = ml0 + lg * 4 + j;
            const float mk = mask_lds[ml];
            float sp = 0.f;
#pragma unroll
            for (int nt = 0; nt < 4; ++nt) {
                float a = acc[nt][j] + bbr[nt];
                a = fmaxf(a, 0.f);
                sp = fmaf(a, wsr[nt], sp);
                pool_part[nt] = fmaf(a, mk, pool_part[nt]);
            }
            sp += __shfl_xor(sp, 1);
            sp += __shfl_xor(sp, 2);
            sp += __shfl_xor(sp, 4);
            sp += __shfl_xor(sp, 8);
            if (ln15 == 0) srow[ml] = sp + bsh;
        }
    }

#pragma unroll
    for (int nt = 0; nt < 4; ++nt) {
        float p = pool_part[nt];
        p += __shfl_xor(p, 16);
        p += __shfl_xor(p, 32);
        if (lane < 16) pool_red[w][nt * 16 + lane] = p;
    }
    __syncthreads();
    if (t < 64)
        pool_pt[(size_t)bid * 64 + t] =
            pool_red[0][t] + pool_red[1][t] + pool_red[2][t] + pool_red[3][t];
}

// ---------------------------------------------------------------------------
// B2: softmax (in place) + pool finalize + channel gate. grid 512 = (b,h)
// ---------------------------------------------------------------------------
__global__ __launch_bounds__(256) void b2_softmax(
    float* __restrict__ score, const float* __restrict__ pool_pt,
    const float* __restrict__ mask,
    const float* __restrict__ Wc, const float* __restrict__ bc,
    float* __restrict__ chan)
{
    const int t = threadIdx.x;
    const int bid = blockIdx.x;           // b*8 + h
    const int b = bid >> 3;
    const int h = bid & 7;
    const int w = t >> 6, lane = t & 63;

    __shared__ float red4[4];
    __shared__ float pool2[64];

    // mask sum
    const float4 mk4 = *(const float4*)&mask[b * 1024 + t * 4];
    float msp = mk4.x + mk4.y + mk4.z + mk4.w;
#pragma unroll
    for (int m = 32; m >= 1; m >>= 1) msp += __shfl_xor(msp, m);
    if (lane == 0) red4[w] = msp;
    __syncthreads();
    const float msum = red4[0] + red4[1] + red4[2] + red4[3];

    // masked scores + max
    float4 s4 = *(const float4*)&score[(size_t)bid * 1024 + t * 4];
    s4.x = (mk4.x == 0.f) ? -1e9f : s4.x;
    s4.y = (mk4.y == 0.f) ? -1e9f : s4.y;
    s4.z = (mk4.z == 0.f) ? -1e9f : s4.z;
    s4.w = (mk4.w == 0.f) ? -1e9f : s4.w;
    float mymax = fmaxf(fmaxf(s4.x, s4.y), fmaxf(s4.z, s4.w));
#pragma unroll
    for (int m = 32; m >= 1; m >>= 1) mymax = fmaxf(mymax, __shfl_xor(mymax, m));
    __syncthreads();
    if (lane == 0) red4[w] = mymax;
    if (t < 64) {
        const float pp = pool_pt[(size_t)(bid * 4) * 64 + t] + pool_pt[(size_t)(bid * 4 + 1) * 64 + t]
                       + pool_pt[(size_t)(bid * 4 + 2) * 64 + t] + pool_pt[(size_t)(bid * 4 + 3) * 64 + t];
        pool2[t] = pp / msum;
    }
    __syncthreads();
    const float gmax = fmaxf(fmaxf(red4[0], red4[1]), fmaxf(red4[2], red4[3]));
    float4 e4;
    e4.x = expf(s4.x - gmax);
    e4.y = expf(s4.y - gmax);
    e4.z = expf(s4.z - gmax);
    e4.w = expf(s4.w - gmax);
    float esp = e4.x + e4.y + e4.z + e4.w;
#pragma unroll
    for (int m = 32; m >= 1; m >>= 1) esp += __shfl_xor(esp, m);
    __syncthreads();
    if (lane == 0) red4[w] = esp;
    __syncthreads();
    const float einv = 1.f / (red4[0] + red4[1] + red4[2] + red4[3]);
    e4.x *= einv; e4.y *= einv; e4.z *= einv; e4.w *= einv;
    *(float4*)&score[(size_t)bid * 1024 + t * 4] = e4;

    // channel gate: chan[bid][d] = sigmoid(bc + sum_o pool2[o]*Wc[h][o][d])
    if (t < 128) {
        const int d = t;
        float ac = bc[h * 128 + d];
#pragma unroll 8
        for (int o = 0; o < 64; ++o)
            ac = fmaf(pool2[o], Wc[h * 8192 + o * 128 + d], ac);
        chan[(size_t)bid * 128 + d] = 1.f / (1.f + expf(-ac));
    }
}

// ---------------------------------------------------------------------------
// B3: partial att over 256 V-rows. grid 2048 = (b,h,chunk)
// ---------------------------------------------------------------------------
__global__ __launch_bounds__(256) void b3_pv(
    const float* __restrict__ pat, const float* __restrict__ score,
    float* __restrict__ attp)
{
    const int t = threadIdx.x;
    const int bid = blockIdx.x;
    const int b = bid >> 5;
    const int h = (bid >> 2) & 7;
    const int chunk = bid & 3;
    const int w = t >> 6, lane = t & 63;
    const int dg = t & 31, rwg = t >> 5;

    __shared__ float p_lds[256];
    __shared__ float att_red[4][128];

    if (t < 256) p_lds[t] = score[(size_t)(bid >> 2) * 1024 + chunk * 256 + t];
    __syncthreads();

    const float* __restrict__ patv = pat + (size_t)b * NM * 2048 + 1024 + h * 128
                                   + (size_t)chunk * 256 * 2048;
    float4 a4 = {0.f, 0.f, 0.f, 0.f};
#pragma unroll 4
    for (int mt = 0; mt < 32; ++mt) {
        const int ml = mt * 8 + rwg;
        const float4 v = *(const float4*)&patv[(size_t)ml * 2048 + dg * 4];
        const float pw = p_lds[ml];
        a4.x = fmaf(pw, v.x, a4.x);
        a4.y = fmaf(pw, v.y, a4.y);
        a4.z = fmaf(pw, v.z, a4.z);
        a4.w = fmaf(pw, v.w, a4.w);
    }
    a4.x += __shfl_xor(a4.x, 32);
    a4.y += __shfl_xor(a4.y, 32);
    a4.z += __shfl_xor(a4.z, 32);
    a4.w += __shfl_xor(a4.w, 32);
    if (lane < 32) *(float4*)&att_red[w][dg * 4] = a4;
    __syncthreads();

    if (t < 128)
        attp[(size_t)bid * 128 + t] =
            att_red[0][t] + att_red[1][t] + att_red[2][t] + att_red[3][t];
}

// ---------------------------------------------------------------------------
// B4: reduce chunks * chan * v1. grid 64 = b, block 256
// ---------------------------------------------------------------------------
__global__ __launch_bounds__(256) void b4_final(
    const float* __restrict__ attp, const float* __restrict__ chan,
    const float* __restrict__ v1, float* __restrict__ att_out)
{
    const int t = threadIdx.x;
    const int b = blockIdx.x;
#pragma unroll
    for (int it = 0; it < 4; ++it) {
        const int idx = it * 256 + t;     // h*128 + d
        const int h = idx >> 7, d = idx & 127;
        const size_t base = ((size_t)(b * 8 + h) * 4) * 128 + d;
        const float av = attp[base] + attp[base + 128] + attp[base + 256] + attp[base + 384];
        att_out[b * 1024 + idx] = av * chan[(size_t)(b * 8 + h) * 128 + d] * v1[b * 1024 + idx];
    }
}

// ---------------------------------------------------------------------------
// C1: partial[kq] = x_kq @ Wt_kq  (K split in 16, 128 each).
// grid 512 = (kq 16) x (32-col chunks), block 256
// ---------------------------------------------------------------------------
__global__ __launch_bounds__(256) void c1_partial(
    const float* __restrict__ h, const float* __restrict__ att,
    const float* __restrict__ Wt, float* __restrict__ part)
{
    const int t = threadIdx.x;
    const int kq = blockIdx.x >> 5;
    const int cc = (blockIdx.x & 31) * 32;
    const int col = cc + (t & 31);
    const int rowg = t >> 5;
    const float* __restrict__ x = (kq < 8) ? h : att;
    const int kbase = (kq & 7) * 128;

    __shared__ float xs[64][68];
    float acc[8];
#pragma unroll
    for (int j = 0; j < 8; ++j) acc[j] = 0.f;

    for (int k0 = 0; k0 < 128; k0 += 64) {
        {
            const int r = t >> 2, b0 = (t & 3) * 16;
#pragma unroll
            for (int u = 0; u < 4; ++u) {
                float4 v = *(const float4*)&x[r * 1024 + kbase + k0 + b0 + 4 * u];
                *(float4*)&xs[r][b0 + 4 * u] = v;
            }
        }
        __syncthreads();
#pragma unroll 8
        for (int kl = 0; kl < 64; ++kl) {
            const float wv = Wt[(size_t)(kq * 128 + k0 + kl) * 1024 + col];
#pragma unroll
            for (int j = 0; j < 8; ++j)
                acc[j] = fmaf(xs[rowg * 8 + j][kl], wv, acc[j]);
        }
        __syncthreads();
    }
#pragma unroll
    for (int j = 0; j < 8; ++j)
        part[(size_t)kq * 65536 + (rowg * 8 + j) * 1024 + col] = acc[j];
}

// ---------------------------------------------------------------------------
// C2: sum 16 partials + bt, LayerNorm (ddof=0). grid 64 rows, block 256
// ---------------------------------------------------------------------------
__global__ __launch_bounds__(256) void c2_ln(
    const float* __restrict__ part, const float* __restrict__ bt,
    const float* __restrict__ lnw, const float* __restrict__ lnb,
    float* __restrict__ out)
{
    const int t = threadIdx.x;
    const int row = blockIdx.x;
    const int w = t >> 6, lane = t & 63;
    __shared__ float red[4];

    float4 v = *(const float4*)&bt[t * 4];
#pragma unroll
    for (int qd = 0; qd < 16; ++qd) {
        const float4 p = *(const float4*)&part[(size_t)qd * 65536 + row * 1024 + t * 4];
        v.x += p.x; v.y += p.y; v.z += p.z; v.w += p.w;
    }
    float s = v.x + v.y + v.z + v.w;
#pragma unroll
    for (int m = 32; m >= 1; m >>= 1) s += __shfl_xor(s, m);
    if (lane == 0) red[w] = s;
    __syncthreads();
    const float mean = (red[0] + red[1] + red[2] + red[3]) * (1.f / 1024.f);
    __syncthreads();
    const float d0 = v.x - mean, d1 = v.y - mean, d2 = v.z - mean, d3 = v.w - mean;
    float ss = d0 * d0 + d1 * d1 + d2 * d2 + d3 * d3;
#pragma unroll
    for (int m = 32; m >= 1; m >>= 1) ss += __shfl_xor(ss, m);
    if (lane == 0) red[w] = ss;
    __syncthreads();
    const float var = (red[0] + red[1] + red[2] + red[3]) * (1.f / 1024.f);
    const float inv = rsqrtf(var + 1e-5f);
    const float4 w4 = *(const float4*)&lnw[t * 4];
    const float4 b4 = *(const float4*)&lnb[t * 4];
    float4 y;
    y.x = d0 * inv * w4.x + b4.x;
    y.y = d1 * inv * w4.y + b4.y;
    y.z = d2 * inv * w4.z + b4.z;
    y.w = d3 * inv * w4.w + b4.w;
    *(float4*)&out[row * 1024 + t * 4] = y;
}

// ---------------------------------------------------------------------------
extern "C" void kernel_launch(void* const* d_in, const int* in_sizes, int n_in,
                              void* d_out, int out_size, void* d_ws, size_t ws_size,
                              hipStream_t stream)
{
    const float* h_state  = (const float*)d_in[0];
    // d_in[1] = att_feats: UNUSED by the reference — never read
    const float* att_mask = (const float*)d_in[2];
    const float* pat      = (const float*)d_in[3];
    const float* Wq       = (const float*)d_in[4];
    const float* bq       = (const float*)d_in[5];
    const float* gnw_q    = (const float*)d_in[6];
    const float* gnb_q    = (const float*)d_in[7];
    const float* Wv1      = (const float*)d_in[8];
    const float* bv1      = (const float*)d_in[9];
    const float* gnw_v1   = (const float*)d_in[10];
    const float* gnb_v1   = (const float*)d_in[11];
    const float* Wb       = (const float*)d_in[12];
    const float* bb       = (const float*)d_in[13];
    const float* Ws       = (const float*)d_in[14];
    const float* bs       = (const float*)d_in[15];
    const float* Wc       = (const float*)d_in[16];
    const float* bc       = (const float*)d_in[17];
    const float* Wt       = (const float*)d_in[18];
    const float* bt       = (const float*)d_in[19];
    const float* lnw      = (const float*)d_in[20];
    const float* lnb      = (const float*)d_in[21];
    float* out = (float*)d_out;

    float* ws     = (float*)d_ws;
    float* qbuf   = ws;                    // 64K floats
    float* v1buf  = ws + 65536;            // 64K
    float* attb   = ws + 131072;           // 64K
    float* parts  = ws + 196608;           // 16 x 64K = 1M floats
    float* score  = ws + 1245184;          // 512K (scores -> p, in place)
    float* pool_pt= ws + 1769472;          // 512*4*64 = 128K
    float* chan   = ws + 1900544;          // 64K
    float* attp   = ws + 1966080;          // 2048*128 = 256K

    a1_partial<<<512, 256, 0, stream>>>(h_state, Wq, Wv1, parts);
    a2_fused<<<128, 256, 0, stream>>>(parts, bq, bv1, gnw_q, gnb_q, gnw_v1, gnb_v1,
                                      qbuf, v1buf);
    b1_scores<<<2048, 256, 0, stream>>>(pat, att_mask, qbuf, Wb, bb, Ws, bs,
                                        score, pool_pt);
    b2_softmax<<<512, 256, 0, stream>>>(score, pool_pt, att_mask, Wc, bc, chan);
    b3_pv<<<2048, 256, 0, stream>>>(pat, score, attp);
    b4_final<<<64, 256, 0, stream>>>(attp, chan, v1buf, attb);
    c1_partial<<<512, 256, 0, stream>>>(h_state, attb, Wt, parts);
    c2_ln<<<64, 256, 0, stream>>>(parts, bt, lnw, lnb, out);
}

// Round 6
// 200.862 us; speedup vs baseline: 3.3705x; 1.0284x over previous
//
#include <hip/hip_runtime.h>
#include <hip/hip_bf16.h>
#include <cmath>

#define NB 64
#define NM 1024
#define NE 1024
#define NH 8
#define NHD 128
#define NMID 64
#define CELU_ALPHA 1.3f

typedef __attribute__((ext_vector_type(8))) short bf16x8;
typedef __attribute__((ext_vector_type(4))) float f32x4;

__device__ __forceinline__ float celuf(float x) {
    return x > 0.f ? x : CELU_ALPHA * expm1f(x / CELU_ALPHA);
}

__device__ __forceinline__ short f2bf(float x) {
    __hip_bfloat16 b = __float2bfloat16(x);
    return *reinterpret_cast<short*>(&b);
}

// ---------------------------------------------------------------------------
// A1: partial GEMM for qpre/v1pre, K split x8.
// grid 512 = (mat 2) x (kq 8) x (32-col chunks), block 256
// ---------------------------------------------------------------------------
__global__ __launch_bounds__(256) void a1_partial(
    const float* __restrict__ h, const float* __restrict__ Wq,
    const float* __restrict__ Wv1, float* __restrict__ partA)
{
    const int t = threadIdx.x;
    const int mat = blockIdx.x >> 8;
    const int kq = (blockIdx.x >> 5) & 7;
    const int cc = (blockIdx.x & 31) * 32;
    const int kbase = kq * 128;
    const float* __restrict__ W = mat ? Wv1 : Wq;

    __shared__ float hs[64][68];
    const int col = cc + (t & 31);
    const int rowg = t >> 5;

    float acc[8];
#pragma unroll
    for (int j = 0; j < 8; ++j) acc[j] = 0.f;

    for (int k0 = 0; k0 < 128; k0 += 64) {
        {
            const int r = t >> 2, b0 = (t & 3) * 16;
#pragma unroll
            for (int u = 0; u < 4; ++u) {
                float4 v = *(const float4*)&h[r * 1024 + kbase + k0 + b0 + 4 * u];
                *(float4*)&hs[r][b0 + 4 * u] = v;
            }
        }
        __syncthreads();
#pragma unroll 8
        for (int kl = 0; kl < 64; ++kl) {
            const float wv = W[(size_t)(kbase + k0 + kl) * 1024 + col];
#pragma unroll
            for (int j = 0; j < 8; ++j)
                acc[j] = fmaf(hs[rowg * 8 + j][kl], wv, acc[j]);
        }
        __syncthreads();
    }
    float* __restrict__ out = partA + (size_t)(mat * 8 + kq) * 65536;
#pragma unroll
    for (int j = 0; j < 8; ++j)
        out[(rowg * 8 + j) * 1024 + col] = acc[j];
}

// ---------------------------------------------------------------------------
// A2: sum 8 partials + bias + CELU + group norm (G=8, ddof=1).
// ---------------------------------------------------------------------------
__global__ __launch_bounds__(256) void a2_fused(
    const float* __restrict__ partA,
    const float* __restrict__ bq, const float* __restrict__ bv1,
    const float* __restrict__ gnw_q, const float* __restrict__ gnb_q,
    const float* __restrict__ gnw_v, const float* __restrict__ gnb_v,
    float* __restrict__ qbuf, float* __restrict__ v1buf)
{
    const int t = threadIdx.x;
    const int mat = blockIdx.x >> 6;
    const int row = blockIdx.x & 63;
    float* __restrict__ outb = mat ? v1buf : qbuf;
    const float* __restrict__ bias = mat ? bv1 : bq;
    const float* __restrict__ gw = mat ? gnw_v : gnw_q;
    const float* __restrict__ gb = mat ? gnb_v : gnb_q;

    float4 x = *(const float4*)&bias[t * 4];
#pragma unroll
    for (int kq = 0; kq < 8; ++kq) {
        const float4 p = *(const float4*)&partA[(size_t)(mat * 8 + kq) * 65536 + row * 1024 + t * 4];
        x.x += p.x; x.y += p.y; x.z += p.z; x.w += p.w;
    }
    x.x = celuf(x.x); x.y = celuf(x.y); x.z = celuf(x.z); x.w = celuf(x.w);

    float s = x.x + x.y + x.z + x.w;
#pragma unroll
    for (int m = 16; m >= 1; m >>= 1) s += __shfl_xor(s, m);
    const float mean = s * (1.f / 128.f);
    const float d0 = x.x - mean, d1 = x.y - mean, d2 = x.z - mean, d3 = x.w - mean;
    float ss = d0 * d0 + d1 * d1 + d2 * d2 + d3 * d3;
#pragma unroll
    for (int m = 16; m >= 1; m >>= 1) ss += __shfl_xor(ss, m);
    const float inv = rsqrtf(ss * (1.f / 127.f) + 1e-5f);
    const float4 w4 = *(const float4*)&gw[t * 4];
    const float4 b4 = *(const float4*)&gb[t * 4];
    float4 y;
    y.x = d0 * inv * w4.x + b4.x;
    y.y = d1 * inv * w4.y + b4.y;
    y.z = d2 * inv * w4.z + b4.z;
    y.w = d3 * inv * w4.w + b4.w;
    *(float4*)&outb[row * 1024 + t * 4] = y;
}

// ---------------------------------------------------------------------------
// B0: precompute wbq_g[(b*8+h)][o][i] = bf16(q[b,h,i] * Wb[h][i][o])
// grid 512 = (b,h), block 256. Fragment-ready layout: row o, 128 bf16 per row.
// ---------------------------------------------------------------------------
__global__ __launch_bounds__(256) void b0_wbq(
    const float* __restrict__ q, const float* __restrict__ Wb,
    short* __restrict__ wbq_g)
{
    const int bid = blockIdx.x;
    const int b = bid >> 3, h = bid & 7;
    const int t = threadIdx.x;
    __shared__ float q_lds[128];
    if (t < 128) q_lds[t] = q[b * 1024 + h * 128 + t];
    __syncthreads();

    const int o = t >> 2;
    const int i0 = (t & 3) * 32;
    union { short s[32]; uint4 q4[4]; } u;
#pragma unroll 8
    for (int v = 0; v < 32; ++v) {
        const int i = i0 + v;
        u.s[v] = f2bf(q_lds[i] * Wb[h * 8192 + i * 64 + o]);
    }
    uint4* dst = (uint4*)&wbq_g[(size_t)bid * 8192 + o * 128 + i0];
#pragma unroll
    for (int r = 0; r < 4; ++r) dst[r] = u.q4[r];
}

// ---------------------------------------------------------------------------
// B: fused flash-style streaming over K and V halves. grid 2048 = (b,h,chunk)
// Per 256-row chunk: s_m = relu(K wbq + bb).Ws ; e_m = exp(s_m + bs) (no max-
// sub; masked -> 0); accumulate av += e_m * v2[m], esum += e_m, pool += am*mk.
// ---------------------------------------------------------------------------
__global__ __launch_bounds__(256) void b_fused(
    const float* __restrict__ pat, const float* __restrict__ mask,
    const short* __restrict__ wbq_g,
    const float* __restrict__ bb, const float* __restrict__ Ws,
    const float* __restrict__ bs,
    float* __restrict__ pool_pt, float* __restrict__ esum_pt,
    float* __restrict__ av_pt)
{
    const int t = threadIdx.x;
    const int bid = blockIdx.x;
    const int b = bid >> 5;
    const int h = (bid >> 2) & 7;
    const int chunk = bid & 3;
    const int w = t >> 6;
    const int lane = t & 63;
    const int ln15 = lane & 15;
    const int lg = lane >> 4;
    const int dg = lane & 31;
    const int rwg = lane >> 5;

    __shared__ float mask_lds[256];
    __shared__ float e_lds[4][16];
    __shared__ float att_red[4][128];
    __shared__ float pool_red[4][64];
    __shared__ float esum_red[4];

    mask_lds[t] = mask[b * 1024 + chunk * 256 + t];

    // B-fragments: 4 coalesced 16B loads per (nt,ks) from precomputed wbq
    const short* __restrict__ wb = wbq_g + (size_t)(bid >> 2) * 8192;
    bf16x8 bfr[4][4];
#pragma unroll
    for (int nt = 0; nt < 4; ++nt)
#pragma unroll
        for (int ks = 0; ks < 4; ++ks)
            bfr[nt][ks] = *(const bf16x8*)&wb[(nt * 16 + ln15) * 128 + ks * 32 + lg * 8];

    float wsr[4], bbr[4];
#pragma unroll
    for (int nt = 0; nt < 4; ++nt) {
        wsr[nt] = Ws[h * 64 + nt * 16 + ln15];
        bbr[nt] = bb[h * 64 + nt * 16 + ln15];
    }
    const float bsh = bs[h];
    float pool_part[4] = {0.f, 0.f, 0.f, 0.f};
    float esum_part = 0.f;
    float4 a4 = {0.f, 0.f, 0.f, 0.f};

    const float* __restrict__ patk = pat + (size_t)b * NM * 2048 + h * 128;
    const float* __restrict__ patv = patk + 1024;

    __syncthreads();   // mask_lds ready

    for (int it = 0; it < 4; ++it) {
        const int ml0 = (w * 4 + it) * 16;       // row within chunk
        const int m0 = chunk * 256 + ml0;        // global row

        // ---- scores for 16 rows (MFMA) ----
        const float* __restrict__ rowp = patk + (size_t)(m0 + ln15) * 2048 + lg * 8;
        bf16x8 af[4];
#pragma unroll
        for (int ks = 0; ks < 4; ++ks) {
            const float4 x = *(const float4*)(rowp + ks * 32);
            const float4 y = *(const float4*)(rowp + ks * 32 + 4);
            union { bf16x8 v; short s[8]; } u8;
            u8.s[0] = f2bf(x.x); u8.s[1] = f2bf(x.y);
            u8.s[2] = f2bf(x.z); u8.s[3] = f2bf(x.w);
            u8.s[4] = f2bf(y.x); u8.s[5] = f2bf(y.y);
            u8.s[6] = f2bf(y.z); u8.s[7] = f2bf(y.w);
            af[ks] = u8.v;
        }

        f32x4 acc[4];
#pragma unroll
        for (int nt = 0; nt < 4; ++nt) acc[nt] = (f32x4){0.f, 0.f, 0.f, 0.f};
#pragma unroll
        for (int ks = 0; ks < 4; ++ks)
#pragma unroll
            for (int nt = 0; nt < 4; ++nt)
                acc[nt] = __builtin_amdgcn_mfma_f32_16x16x32_bf16(af[ks], bfr[nt][ks], acc[nt], 0, 0, 0);

        // ---- epilogue: bias+relu, score dot Ws, pool, e = exp ----
#pragma unroll
        for (int j = 0; j < 4; ++j) {
            const int ml = ml0 + lg * 4 + j;
            const float mk = mask_lds[ml];
            float sp = 0.f;
#pragma unroll
            for (int nt = 0; nt < 4; ++nt) {
                float a = acc[nt][j] + bbr[nt];
                a = fmaxf(a, 0.f);
                sp = fmaf(a, wsr[nt], sp);
                pool_part[nt] = fmaf(a, mk, pool_part[nt]);
            }
            sp += __shfl_xor(sp, 1);
            sp += __shfl_xor(sp, 2);
            sp += __shfl_xor(sp, 4);
            sp += __shfl_xor(sp, 8);
            if (ln15 == 0) {
                const float e = (mk == 0.f) ? 0.f : expf(sp + bsh);
                e_lds[w][lg * 4 + j] = e;    // wave-local, no barrier needed
                esum_part += e;
            }
        }

        // ---- V accumulate for the same 16 rows ----
        const float* __restrict__ vrow = patv + (size_t)(m0 + rwg) * 2048 + dg * 4;
#pragma unroll
        for (int r = 0; r < 8; ++r) {
            const float4 v = *(const float4*)(vrow + (size_t)(2 * r) * 2048);
            const float e = e_lds[w][rwg + 2 * r];
            a4.x = fmaf(e, v.x, a4.x);
            a4.y = fmaf(e, v.y, a4.y);
            a4.z = fmaf(e, v.z, a4.z);
            a4.w = fmaf(e, v.w, a4.w);
        }
    }

    // ---- reductions ----
    a4.x += __shfl_xor(a4.x, 32);
    a4.y += __shfl_xor(a4.y, 32);
    a4.z += __shfl_xor(a4.z, 32);
    a4.w += __shfl_xor(a4.w, 32);
    if (lane < 32) *(float4*)&att_red[w][dg * 4] = a4;

#pragma unroll
    for (int nt = 0; nt < 4; ++nt) {
        float p = pool_part[nt];
        p += __shfl_xor(p, 16);
        p += __shfl_xor(p, 32);
        if (lane < 16) pool_red[w][nt * 16 + lane] = p;
    }

#pragma unroll
    for (int m = 32; m >= 1; m >>= 1) esum_part += __shfl_xor(esum_part, m);
    if (lane == 0) esum_red[w] = esum_part;
    __syncthreads();

    if (t < 128)
        av_pt[(size_t)bid * 128 + t] =
            att_red[0][t] + att_red[1][t] + att_red[2][t] + att_red[3][t];
    else if (t < 192)
        pool_pt[(size_t)bid * 64 + (t - 128)] =
            pool_red[0][t - 128] + pool_red[1][t - 128] + pool_red[2][t - 128] + pool_red[3][t - 128];
    else if (t == 192)
        esum_pt[bid] = esum_red[0] + esum_red[1] + esum_red[2] + esum_red[3];
}

// ---------------------------------------------------------------------------
// B5: finalize. grid 512 = (b,h), block 256.
// att = (sum_c av) / (sum_c esum); pool2 = (sum_c pool)/msum; chan gate; x v1.
// ---------------------------------------------------------------------------
__global__ __launch_bounds__(256) void b5_final(
    const float* __restrict__ pool_pt, const float* __restrict__ esum_pt,
    const float* __restrict__ av_pt, const float* __restrict__ mask,
    const float* __restrict__ Wc, const float* __restrict__ bc,
    const float* __restrict__ v1, float* __restrict__ att_out)
{
    const int t = threadIdx.x;
    const int bid = blockIdx.x;            // b*8 + h
    const int b = bid >> 3;
    const int h = bid & 7;
    const int w = t >> 6, lane = t & 63;

    __shared__ float red4[4];
    __shared__ float pool2[64];

    const float4 mk4 = *(const float4*)&mask[b * 1024 + t * 4];
    float msp = mk4.x + mk4.y + mk4.z + mk4.w;
#pragma unroll
    for (int m = 32; m >= 1; m >>= 1) msp += __shfl_xor(msp, m);
    if (lane == 0) red4[w] = msp;
    __syncthreads();
    const float msum = red4[0] + red4[1] + red4[2] + red4[3];

    if (t < 64) {
        const float pp = pool_pt[(size_t)(bid * 4) * 64 + t] + pool_pt[(size_t)(bid * 4 + 1) * 64 + t]
                       + pool_pt[(size_t)(bid * 4 + 2) * 64 + t] + pool_pt[(size_t)(bid * 4 + 3) * 64 + t];
        pool2[t] = pp / msum;
    }
    __syncthreads();

    if (t < 128) {
        const int d = t;
        const float av = av_pt[(size_t)(bid * 4) * 128 + d] + av_pt[(size_t)(bid * 4 + 1) * 128 + d]
                       + av_pt[(size_t)(bid * 4 + 2) * 128 + d] + av_pt[(size_t)(bid * 4 + 3) * 128 + d];
        const float esum = esum_pt[bid * 4] + esum_pt[bid * 4 + 1]
                         + esum_pt[bid * 4 + 2] + esum_pt[bid * 4 + 3];
        const float att = av / esum;
        float ac = bc[h * 128 + d];
#pragma unroll 8
        for (int o = 0; o < 64; ++o)
            ac = fmaf(pool2[o], Wc[h * 8192 + o * 128 + d], ac);
        const float sig = 1.f / (1.f + expf(-ac));
        att_out[b * 1024 + h * 128 + d] = att * sig * v1[b * 1024 + h * 128 + d];
    }
}

// ---------------------------------------------------------------------------
// C1: partial[kq] = x_kq @ Wt_kq  (K split in 16, 128 each).
// ---------------------------------------------------------------------------
__global__ __launch_bounds__(256) void c1_partial(
    const float* __restrict__ h, const float* __restrict__ att,
    const float* __restrict__ Wt, float* __restrict__ part)
{
    const int t = threadIdx.x;
    const int kq = blockIdx.x >> 5;
    const int cc = (blockIdx.x & 31) * 32;
    const int col = cc + (t & 31);
    const int rowg = t >> 5;
    const float* __restrict__ x = (kq < 8) ? h : att;
    const int kbase = (kq & 7) * 128;

    __shared__ float xs[64][68];
    float acc[8];
#pragma unroll
    for (int j = 0; j < 8; ++j) acc[j] = 0.f;

    for (int k0 = 0; k0 < 128; k0 += 64) {
        {
            const int r = t >> 2, b0 = (t & 3) * 16;
#pragma unroll
            for (int u = 0; u < 4; ++u) {
                float4 v = *(const float4*)&x[r * 1024 + kbase + k0 + b0 + 4 * u];
                *(float4*)&xs[r][b0 + 4 * u] = v;
            }
        }
        __syncthreads();
#pragma unroll 8
        for (int kl = 0; kl < 64; ++kl) {
            const float wv = Wt[(size_t)(kq * 128 + k0 + kl) * 1024 + col];
#pragma unroll
            for (int j = 0; j < 8; ++j)
                acc[j] = fmaf(xs[rowg * 8 + j][kl], wv, acc[j]);
        }
        __syncthreads();
    }
#pragma unroll
    for (int j = 0; j < 8; ++j)
        part[(size_t)kq * 65536 + (rowg * 8 + j) * 1024 + col] = acc[j];
}

// ---------------------------------------------------------------------------
// C2: sum 16 partials + bt, LayerNorm (ddof=0). grid 64 rows, block 256
// ---------------------------------------------------------------------------
__global__ __launch_bounds__(256) void c2_ln(
    const float* __restrict__ part, const float* __restrict__ bt,
    const float* __restrict__ lnw, const float* __restrict__ lnb,
    float* __restrict__ out)
{
    const int t = threadIdx.x;
    const int row = blockIdx.x;
    const int w = t >> 6, lane = t & 63;
    __shared__ float red[4];

    float4 v = *(const float4*)&bt[t * 4];
#pragma unroll
    for (int qd = 0; qd < 16; ++qd) {
        const float4 p = *(const float4*)&part[(size_t)qd * 65536 + row * 1024 + t * 4];
        v.x += p.x; v.y += p.y; v.z += p.z; v.w += p.w;
    }
    float s = v.x + v.y + v.z + v.w;
#pragma unroll
    for (int m = 32; m >= 1; m >>= 1) s += __shfl_xor(s, m);
    if (lane == 0) red[w] = s;
    __syncthreads();
    const float mean = (red[0] + red[1] + red[2] + red[3]) * (1.f / 1024.f);
    __syncthreads();
    const float d0 = v.x - mean, d1 = v.y - mean, d2 = v.z - mean, d3 = v.w - mean;
    float ss = d0 * d0 + d1 * d1 + d2 * d2 + d3 * d3;
#pragma unroll
    for (int m = 32; m >= 1; m >>= 1) ss += __shfl_xor(ss, m);
    if (lane == 0) red[w] = ss;
    __syncthreads();
    const float var = (red[0] + red[1] + red[2] + red[3]) * (1.f / 1024.f);
    const float inv = rsqrtf(var + 1e-5f);
    const float4 w4 = *(const float4*)&lnw[t * 4];
    const float4 b4 = *(const float4*)&lnb[t * 4];
    float4 y;
    y.x = d0 * inv * w4.x + b4.x;
    y.y = d1 * inv * w4.y + b4.y;
    y.z = d2 * inv * w4.z + b4.z;
    y.w = d3 * inv * w4.w + b4.w;
    *(float4*)&out[row * 1024 + t * 4] = y;
}

// ---------------------------------------------------------------------------
extern "C" void kernel_launch(void* const* d_in, const int* in_sizes, int n_in,
                              void* d_out, int out_size, void* d_ws, size_t ws_size,
                              hipStream_t stream)
{
    const float* h_state  = (const float*)d_in[0];
    // d_in[1] = att_feats: UNUSED by the reference — never read
    const float* att_mask = (const float*)d_in[2];
    const float* pat      = (const float*)d_in[3];
    const float* Wq       = (const float*)d_in[4];
    const float* bq       = (const float*)d_in[5];
    const float* gnw_q    = (const float*)d_in[6];
    const float* gnb_q    = (const float*)d_in[7];
    const float* Wv1      = (const float*)d_in[8];
    const float* bv1      = (const float*)d_in[9];
    const float* gnw_v1   = (const float*)d_in[10];
    const float* gnb_v1   = (const float*)d_in[11];
    const float* Wb       = (const float*)d_in[12];
    const float* bb       = (const float*)d_in[13];
    const float* Ws       = (const float*)d_in[14];
    const float* bs       = (const float*)d_in[15];
    const float* Wc       = (const float*)d_in[16];
    const float* bc       = (const float*)d_in[17];
    const float* Wt       = (const float*)d_in[18];
    const float* bt       = (const float*)d_in[19];
    const float* lnw      = (const float*)d_in[20];
    const float* lnb      = (const float*)d_in[21];
    float* out = (float*)d_out;

    float* ws      = (float*)d_ws;
    float* qbuf    = ws;                    // 64K floats
    float* v1buf   = ws + 65536;            // 64K
    float* attb    = ws + 131072;           // 64K
    float* parts   = ws + 196608;           // 16 x 64K = 1M floats
    short* wbq_g   = (short*)(ws + 1245184);// 512*8192 bf16 = 8 MB (2M floats)
    float* pool_pt = ws + 3342336;          // 2048*64
    float* esum_pt = ws + 3473408;          // 2048
    float* av_pt   = ws + 3475456;          // 2048*128

    a1_partial<<<512, 256, 0, stream>>>(h_state, Wq, Wv1, parts);
    a2_fused<<<128, 256, 0, stream>>>(parts, bq, bv1, gnw_q, gnb_q, gnw_v1, gnb_v1,
                                      qbuf, v1buf);
    b0_wbq<<<512, 256, 0, stream>>>(qbuf, Wb, wbq_g);
    b_fused<<<2048, 256, 0, stream>>>(pat, att_mask, wbq_g, bb, Ws, bs,
                                      pool_pt, esum_pt, av_pt);
    b5_final<<<512, 256, 0, stream>>>(pool_pt, esum_pt, av_pt, att_mask,
                                      Wc, bc, v1buf, attb);
    c1_partial<<<512, 256, 0, stream>>>(h_state, attb, Wt, parts);
    c2_ln<<<64, 256, 0, stream>>>(parts, bt, lnw, lnb, out);
}

// Round 7
// 160.767 us; speedup vs baseline: 4.2111x; 1.2494x over previous
//
#include <hip/hip_runtime.h>
#include <hip/hip_bf16.h>
#include <cmath>

#define NB 64
#define NM 1024
#define NE 1024
#define NH 8
#define NHD 128
#define NMID 64
#define CELU_ALPHA 1.3f

typedef __attribute__((ext_vector_type(8))) short bf16x8;
typedef __attribute__((ext_vector_type(4))) float f32x4;

__device__ __forceinline__ float celuf(float x) {
    return x > 0.f ? x : CELU_ALPHA * expm1f(x / CELU_ALPHA);
}

__device__ __forceinline__ short f2bf(float x) {
    __hip_bfloat16 b = __float2bfloat16(x);
    return *reinterpret_cast<short*>(&b);
}

// ---------------------------------------------------------------------------
// A1: LDS-tiled fp32 GEMM partials for q/v1 pre-activations.
// grid 256 = mat(2) x kq(8) x cc(16 of 64 cols), block 256.
// Coalesced staging of W (no more column-walk over-fetch).
// ---------------------------------------------------------------------------
__global__ __launch_bounds__(256) void a1_tile(
    const float* __restrict__ h, const float* __restrict__ Wq,
    const float* __restrict__ Wv1, float* __restrict__ partA)
{
    const int t = threadIdx.x;
    const int mat = blockIdx.x >> 7;
    const int kq = (blockIdx.x >> 4) & 7;
    const int cc = (blockIdx.x & 15) * 64;
    const int kbase = kq * 128;
    const float* __restrict__ W = mat ? Wv1 : Wq;

    __shared__ float wl[128][64];
    __shared__ float hl[64][132];

#pragma unroll
    for (int u = 0; u < 8; ++u) {            // stage W tile: 128x64
        const int f = t + 256 * u;
        const int row = f >> 4, c4 = f & 15;
        *(float4*)&wl[row][c4 * 4] =
            *(const float4*)&W[(size_t)(kbase + row) * 1024 + cc + c4 * 4];
    }
#pragma unroll
    for (int u = 0; u < 8; ++u) {            // stage h tile: 64x128
        const int f = t + 256 * u;
        const int r = f >> 5, k4 = f & 31;
        *(float4*)&hl[r][k4 * 4] = *(const float4*)&h[r * 1024 + kbase + k4 * 4];
    }
    __syncthreads();

    const int r0 = (t >> 4) * 4;
    const int c0 = (t & 15) * 4;
    float acc[4][4];
#pragma unroll
    for (int i = 0; i < 4; ++i)
#pragma unroll
        for (int j = 0; j < 4; ++j) acc[i][j] = 0.f;

#pragma unroll 4
    for (int k = 0; k < 128; ++k) {
        const float4 w4 = *(const float4*)&wl[k][c0];
        const float h0 = hl[r0][k], h1 = hl[r0 + 1][k];
        const float h2 = hl[r0 + 2][k], h3 = hl[r0 + 3][k];
        acc[0][0] = fmaf(h0, w4.x, acc[0][0]); acc[0][1] = fmaf(h0, w4.y, acc[0][1]);
        acc[0][2] = fmaf(h0, w4.z, acc[0][2]); acc[0][3] = fmaf(h0, w4.w, acc[0][3]);
        acc[1][0] = fmaf(h1, w4.x, acc[1][0]); acc[1][1] = fmaf(h1, w4.y, acc[1][1]);
        acc[1][2] = fmaf(h1, w4.z, acc[1][2]); acc[1][3] = fmaf(h1, w4.w, acc[1][3]);
        acc[2][0] = fmaf(h2, w4.x, acc[2][0]); acc[2][1] = fmaf(h2, w4.y, acc[2][1]);
        acc[2][2] = fmaf(h2, w4.z, acc[2][2]); acc[2][3] = fmaf(h2, w4.w, acc[2][3]);
        acc[3][0] = fmaf(h3, w4.x, acc[3][0]); acc[3][1] = fmaf(h3, w4.y, acc[3][1]);
        acc[3][2] = fmaf(h3, w4.z, acc[3][2]); acc[3][3] = fmaf(h3, w4.w, acc[3][3]);
    }

    float* __restrict__ out = partA + (size_t)(mat * 8 + kq) * 65536;
#pragma unroll
    for (int i = 0; i < 4; ++i) {
        float4 v = {acc[i][0], acc[i][1], acc[i][2], acc[i][3]};
        *(float4*)&out[(r0 + i) * 1024 + cc + c0] = v;
    }
}

// ---------------------------------------------------------------------------
// A2B0: per-(b,h) fused: sum partials + bias + CELU + groupnorm (ddof=1)
// for q AND v1 groups, write v1buf, build wbq_g (bf16, fragment-ready).
// grid 512 = (b,h), block 256 (waves 0-1: q, waves 2-3: v1).
// ---------------------------------------------------------------------------
__global__ __launch_bounds__(256) void a2b0(
    const float* __restrict__ partA,
    const float* __restrict__ bq, const float* __restrict__ bv1,
    const float* __restrict__ gnw_q, const float* __restrict__ gnb_q,
    const float* __restrict__ gnw_v, const float* __restrict__ gnb_v,
    const float* __restrict__ Wb,
    float* __restrict__ v1buf, short* __restrict__ wbq_g)
{
    const int bid = blockIdx.x;
    const int b = bid >> 3, hh = bid & 7;
    const int t = threadIdx.x;
    const int mat = t >> 7;          // 0 = q, 1 = v1
    const int c = t & 127;
    const int ch = hh * 128 + c;
    const int w = t >> 6, lane = t & 63;

    __shared__ float q_lds[128];
    __shared__ float red[4][2];

    float x = mat ? bv1[ch] : bq[ch];
#pragma unroll
    for (int kq = 0; kq < 8; ++kq)
        x += partA[(size_t)(mat * 8 + kq) * 65536 + b * 1024 + ch];
    x = celuf(x);

    float s = x, s2 = x * x;
#pragma unroll
    for (int m = 32; m >= 1; m >>= 1) {
        s += __shfl_xor(s, m);
        s2 += __shfl_xor(s2, m);
    }
    if (lane == 0) { red[w][0] = s; red[w][1] = s2; }
    __syncthreads();
    const float S  = red[mat * 2][0] + red[mat * 2 + 1][0];
    const float S2 = red[mat * 2][1] + red[mat * 2 + 1][1];
    const float mean = S * (1.f / 128.f);
    const float var = (S2 - 128.f * mean * mean) * (1.f / 127.f);
    const float inv = rsqrtf(var + 1e-5f);
    const float gw = mat ? gnw_v[ch] : gnw_q[ch];
    const float gb = mat ? gnb_v[ch] : gnb_q[ch];
    const float y = (x - mean) * inv * gw + gb;
    if (mat == 0) q_lds[c] = y;
    else v1buf[b * 1024 + ch] = y;
    __syncthreads();

    // wbq_g[bid][o][i] = bf16(q[i] * Wb[h][i][o]), row-stride 128
    const int o = t >> 2;
    const int i0 = (t & 3) * 32;
    union { short sv[32]; uint4 q4[4]; } u;
#pragma unroll 8
    for (int v = 0; v < 32; ++v) {
        const int i = i0 + v;
        u.sv[v] = f2bf(q_lds[i] * Wb[hh * 8192 + i * 64 + o]);
    }
    uint4* dst = (uint4*)&wbq_g[(size_t)bid * 8192 + o * 128 + i0];
#pragma unroll
    for (int r = 0; r < 4; ++r) dst[r] = u.q4[r];
}

// ---------------------------------------------------------------------------
// B: fused flash-style streaming over K and V halves. grid 2048 = (b,h,chunk)
// V-tile loads prefetched alongside A-tile loads (16 loads in flight/tile).
// ---------------------------------------------------------------------------
__global__ __launch_bounds__(256) void b_fused(
    const float* __restrict__ pat, const float* __restrict__ mask,
    const short* __restrict__ wbq_g,
    const float* __restrict__ bb, const float* __restrict__ Ws,
    const float* __restrict__ bs,
    float* __restrict__ pool_pt, float* __restrict__ esum_pt,
    float* __restrict__ av_pt)
{
    const int t = threadIdx.x;
    const int bid = blockIdx.x;
    const int b = bid >> 5;
    const int h = (bid >> 2) & 7;
    const int chunk = bid & 3;
    const int w = t >> 6;
    const int lane = t & 63;
    const int ln15 = lane & 15;
    const int lg = lane >> 4;
    const int dg = lane & 31;
    const int rwg = lane >> 5;

    __shared__ float mask_lds[256];
    __shared__ float e_lds[4][16];
    __shared__ float att_red[4][128];
    __shared__ float pool_red[4][64];
    __shared__ float esum_red[4];

    mask_lds[t] = mask[b * 1024 + chunk * 256 + t];

    const short* __restrict__ wb = wbq_g + (size_t)(bid >> 2) * 8192;
    bf16x8 bfr[4][4];
#pragma unroll
    for (int nt = 0; nt < 4; ++nt)
#pragma unroll
        for (int ks = 0; ks < 4; ++ks)
            bfr[nt][ks] = *(const bf16x8*)&wb[(nt * 16 + ln15) * 128 + ks * 32 + lg * 8];

    float wsr[4], bbr[4];
#pragma unroll
    for (int nt = 0; nt < 4; ++nt) {
        wsr[nt] = Ws[h * 64 + nt * 16 + ln15];
        bbr[nt] = bb[h * 64 + nt * 16 + ln15];
    }
    const float bsh = bs[h];
    float pool_part[4] = {0.f, 0.f, 0.f, 0.f};
    float esum_part = 0.f;
    float4 a4 = {0.f, 0.f, 0.f, 0.f};

    const float* __restrict__ patk = pat + (size_t)b * NM * 2048 + h * 128;
    const float* __restrict__ patv = patk + 1024;

    __syncthreads();   // mask_lds ready

    for (int it = 0; it < 4; ++it) {
        const int ml0 = (w * 4 + it) * 16;       // row within chunk
        const int m0 = chunk * 256 + ml0;        // global row

        // ---- issue ALL loads for this tile: 8 A + 8 V ----
        const float* __restrict__ rowp = patk + (size_t)(m0 + ln15) * 2048 + lg * 8;
        float4 ax[4], ay[4];
#pragma unroll
        for (int ks = 0; ks < 4; ++ks) {
            ax[ks] = *(const float4*)(rowp + ks * 32);
            ay[ks] = *(const float4*)(rowp + ks * 32 + 4);
        }
        const float* __restrict__ vrow = patv + (size_t)(m0 + rwg) * 2048 + dg * 4;
        float4 vv[8];
#pragma unroll
        for (int r = 0; r < 8; ++r)
            vv[r] = *(const float4*)(vrow + (size_t)(2 * r) * 2048);

        // ---- cvt A to bf16 fragments ----
        bf16x8 af[4];
#pragma unroll
        for (int ks = 0; ks < 4; ++ks) {
            union { bf16x8 v; short s[8]; } u8;
            u8.s[0] = f2bf(ax[ks].x); u8.s[1] = f2bf(ax[ks].y);
            u8.s[2] = f2bf(ax[ks].z); u8.s[3] = f2bf(ax[ks].w);
            u8.s[4] = f2bf(ay[ks].x); u8.s[5] = f2bf(ay[ks].y);
            u8.s[6] = f2bf(ay[ks].z); u8.s[7] = f2bf(ay[ks].w);
            af[ks] = u8.v;
        }

        f32x4 acc[4];
#pragma unroll
        for (int nt = 0; nt < 4; ++nt) acc[nt] = (f32x4){0.f, 0.f, 0.f, 0.f};
#pragma unroll
        for (int ks = 0; ks < 4; ++ks)
#pragma unroll
            for (int nt = 0; nt < 4; ++nt)
                acc[nt] = __builtin_amdgcn_mfma_f32_16x16x32_bf16(af[ks], bfr[nt][ks], acc[nt], 0, 0, 0);

        // ---- epilogue: bias+relu, score dot Ws, pool, e = exp ----
#pragma unroll
        for (int j = 0; j < 4; ++j) {
            const int ml = ml0 + lg * 4 + j;
            const float mk = mask_lds[ml];
            float sp = 0.f;
#pragma unroll
            for (int nt = 0; nt < 4; ++nt) {
                float a = acc[nt][j] + bbr[nt];
                a = fmaxf(a, 0.f);
                sp = fmaf(a, wsr[nt], sp);
                pool_part[nt] = fmaf(a, mk, pool_part[nt]);
            }
            sp += __shfl_xor(sp, 1);
            sp += __shfl_xor(sp, 2);
            sp += __shfl_xor(sp, 4);
            sp += __shfl_xor(sp, 8);
            if (ln15 == 0) {
                const float e = (mk == 0.f) ? 0.f : expf(sp + bsh);
                e_lds[w][lg * 4 + j] = e;    // wave-local (same-wave DS order)
                esum_part += e;
            }
        }

        // ---- V accumulate (loads already in registers) ----
#pragma unroll
        for (int r = 0; r < 8; ++r) {
            const float e = e_lds[w][rwg + 2 * r];
            a4.x = fmaf(e, vv[r].x, a4.x);
            a4.y = fmaf(e, vv[r].y, a4.y);
            a4.z = fmaf(e, vv[r].z, a4.z);
            a4.w = fmaf(e, vv[r].w, a4.w);
        }
    }

    // ---- reductions ----
    a4.x += __shfl_xor(a4.x, 32);
    a4.y += __shfl_xor(a4.y, 32);
    a4.z += __shfl_xor(a4.z, 32);
    a4.w += __shfl_xor(a4.w, 32);
    if (lane < 32) *(float4*)&att_red[w][dg * 4] = a4;

#pragma unroll
    for (int nt = 0; nt < 4; ++nt) {
        float p = pool_part[nt];
        p += __shfl_xor(p, 16);
        p += __shfl_xor(p, 32);
        if (lane < 16) pool_red[w][nt * 16 + lane] = p;
    }

#pragma unroll
    for (int m = 32; m >= 1; m >>= 1) esum_part += __shfl_xor(esum_part, m);
    if (lane == 0) esum_red[w] = esum_part;
    __syncthreads();

    if (t < 128)
        av_pt[(size_t)bid * 128 + t] =
            att_red[0][t] + att_red[1][t] + att_red[2][t] + att_red[3][t];
    else if (t < 192)
        pool_pt[(size_t)bid * 64 + (t - 128)] =
            pool_red[0][t - 128] + pool_red[1][t - 128] + pool_red[2][t - 128] + pool_red[3][t - 128];
    else if (t == 192)
        esum_pt[bid] = esum_red[0] + esum_red[1] + esum_red[2] + esum_red[3];
}

// ---------------------------------------------------------------------------
// B5: finalize. grid 512 = (b,h), block 256.
// ---------------------------------------------------------------------------
__global__ __launch_bounds__(256) void b5_final(
    const float* __restrict__ pool_pt, const float* __restrict__ esum_pt,
    const float* __restrict__ av_pt, const float* __restrict__ mask,
    const float* __restrict__ Wc, const float* __restrict__ bc,
    const float* __restrict__ v1, float* __restrict__ att_out)
{
    const int t = threadIdx.x;
    const int bid = blockIdx.x;            // b*8 + h
    const int b = bid >> 3;
    const int h = bid & 7;
    const int w = t >> 6, lane = t & 63;

    __shared__ float red4[4];
    __shared__ float pool2[64];

    const float4 mk4 = *(const float4*)&mask[b * 1024 + t * 4];
    float msp = mk4.x + mk4.y + mk4.z + mk4.w;
#pragma unroll
    for (int m = 32; m >= 1; m >>= 1) msp += __shfl_xor(msp, m);
    if (lane == 0) red4[w] = msp;
    __syncthreads();
    const float msum = red4[0] + red4[1] + red4[2] + red4[3];

    if (t < 64) {
        const float pp = pool_pt[(size_t)(bid * 4) * 64 + t] + pool_pt[(size_t)(bid * 4 + 1) * 64 + t]
                       + pool_pt[(size_t)(bid * 4 + 2) * 64 + t] + pool_pt[(size_t)(bid * 4 + 3) * 64 + t];
        pool2[t] = pp / msum;
    }
    __syncthreads();

    if (t < 128) {
        const int d = t;
        const float av = av_pt[(size_t)(bid * 4) * 128 + d] + av_pt[(size_t)(bid * 4 + 1) * 128 + d]
                       + av_pt[(size_t)(bid * 4 + 2) * 128 + d] + av_pt[(size_t)(bid * 4 + 3) * 128 + d];
        const float esum = esum_pt[bid * 4] + esum_pt[bid * 4 + 1]
                         + esum_pt[bid * 4 + 2] + esum_pt[bid * 4 + 3];
        const float att = av / esum;
        float ac = bc[h * 128 + d];
#pragma unroll 8
        for (int o = 0; o < 64; ++o)
            ac = fmaf(pool2[o], Wc[h * 8192 + o * 128 + d], ac);
        const float sig = 1.f / (1.f + expf(-ac));
        att_out[b * 1024 + h * 128 + d] = att * sig * v1[b * 1024 + h * 128 + d];
    }
}

// ---------------------------------------------------------------------------
// C1: LDS-tiled fp32 GEMM partials for out = [h | att] @ Wt.
// grid 256 = kq(16) x cc(16 of 64 cols), block 256.
// ---------------------------------------------------------------------------
__global__ __launch_bounds__(256) void c1_tile(
    const float* __restrict__ h, const float* __restrict__ att,
    const float* __restrict__ Wt, float* __restrict__ part)
{
    const int t = threadIdx.x;
    const int kq = blockIdx.x >> 4;
    const int cc = (blockIdx.x & 15) * 64;
    const float* __restrict__ x = (kq < 8) ? h : att;
    const int kbase = (kq & 7) * 128;

    __shared__ float wl[128][64];
    __shared__ float hl[64][132];

#pragma unroll
    for (int u = 0; u < 8; ++u) {
        const int f = t + 256 * u;
        const int row = f >> 4, c4 = f & 15;
        *(float4*)&wl[row][c4 * 4] =
            *(const float4*)&Wt[(size_t)(kq * 128 + row) * 1024 + cc + c4 * 4];
    }
#pragma unroll
    for (int u = 0; u < 8; ++u) {
        const int f = t + 256 * u;
        const int r = f >> 5, k4 = f & 31;
        *(float4*)&hl[r][k4 * 4] = *(const float4*)&x[r * 1024 + kbase + k4 * 4];
    }
    __syncthreads();

    const int r0 = (t >> 4) * 4;
    const int c0 = (t & 15) * 4;
    float acc[4][4];
#pragma unroll
    for (int i = 0; i < 4; ++i)
#pragma unroll
        for (int j = 0; j < 4; ++j) acc[i][j] = 0.f;

#pragma unroll 4
    for (int k = 0; k < 128; ++k) {
        const float4 w4 = *(const float4*)&wl[k][c0];
        const float h0 = hl[r0][k], h1 = hl[r0 + 1][k];
        const float h2 = hl[r0 + 2][k], h3 = hl[r0 + 3][k];
        acc[0][0] = fmaf(h0, w4.x, acc[0][0]); acc[0][1] = fmaf(h0, w4.y, acc[0][1]);
        acc[0][2] = fmaf(h0, w4.z, acc[0][2]); acc[0][3] = fmaf(h0, w4.w, acc[0][3]);
        acc[1][0] = fmaf(h1, w4.x, acc[1][0]); acc[1][1] = fmaf(h1, w4.y, acc[1][1]);
        acc[1][2] = fmaf(h1, w4.z, acc[1][2]); acc[1][3] = fmaf(h1, w4.w, acc[1][3]);
        acc[2][0] = fmaf(h2, w4.x, acc[2][0]); acc[2][1] = fmaf(h2, w4.y, acc[2][1]);
        acc[2][2] = fmaf(h2, w4.z, acc[2][2]); acc[2][3] = fmaf(h2, w4.w, acc[2][3]);
        acc[3][0] = fmaf(h3, w4.x, acc[3][0]); acc[3][1] = fmaf(h3, w4.y, acc[3][1]);
        acc[3][2] = fmaf(h3, w4.z, acc[3][2]); acc[3][3] = fmaf(h3, w4.w, acc[3][3]);
    }

#pragma unroll
    for (int i = 0; i < 4; ++i) {
        float4 v = {acc[i][0], acc[i][1], acc[i][2], acc[i][3]};
        *(float4*)&part[(size_t)kq * 65536 + (r0 + i) * 1024 + cc + c0] = v;
    }
}

// ---------------------------------------------------------------------------
// C2: sum 16 partials + bt, LayerNorm (ddof=0). grid 64 rows, block 256
// ---------------------------------------------------------------------------
__global__ __launch_bounds__(256) void c2_ln(
    const float* __restrict__ part, const float* __restrict__ bt,
    const float* __restrict__ lnw, const float* __restrict__ lnb,
    float* __restrict__ out)
{
    const int t = threadIdx.x;
    const int row = blockIdx.x;
    const int w = t >> 6, lane = t & 63;
    __shared__ float red[4];

    float4 v = *(const float4*)&bt[t * 4];
#pragma unroll
    for (int qd = 0; qd < 16; ++qd) {
        const float4 p = *(const float4*)&part[(size_t)qd * 65536 + row * 1024 + t * 4];
        v.x += p.x; v.y += p.y; v.z += p.z; v.w += p.w;
    }
    float s = v.x + v.y + v.z + v.w;
#pragma unroll
    for (int m = 32; m >= 1; m >>= 1) s += __shfl_xor(s, m);
    if (lane == 0) red[w] = s;
    __syncthreads();
    const float mean = (red[0] + red[1] + red[2] + red[3]) * (1.f / 1024.f);
    __syncthreads();
    const float d0 = v.x - mean, d1 = v.y - mean, d2 = v.z - mean, d3 = v.w - mean;
    float ss = d0 * d0 + d1 * d1 + d2 * d2 + d3 * d3;
#pragma unroll
    for (int m = 32; m >= 1; m >>= 1) ss += __shfl_xor(ss, m);
    if (lane == 0) red[w] = ss;
    __syncthreads();
    const float var = (red[0] + red[1] + red[2] + red[3]) * (1.f / 1024.f);
    const float inv = rsqrtf(var + 1e-5f);
    const float4 w4 = *(const float4*)&lnw[t * 4];
    const float4 b4 = *(const float4*)&lnb[t * 4];
    float4 y;
    y.x = d0 * inv * w4.x + b4.x;
    y.y = d1 * inv * w4.y + b4.y;
    y.z = d2 * inv * w4.z + b4.z;
    y.w = d3 * inv * w4.w + b4.w;
    *(float4*)&out[row * 1024 + t * 4] = y;
}

// ---------------------------------------------------------------------------
extern "C" void kernel_launch(void* const* d_in, const int* in_sizes, int n_in,
                              void* d_out, int out_size, void* d_ws, size_t ws_size,
                              hipStream_t stream)
{
    const float* h_state  = (const float*)d_in[0];
    // d_in[1] = att_feats: UNUSED by the reference — never read
    const float* att_mask = (const float*)d_in[2];
    const float* pat      = (const float*)d_in[3];
    const float* Wq       = (const float*)d_in[4];
    const float* bq       = (const float*)d_in[5];
    const float* gnw_q    = (const float*)d_in[6];
    const float* gnb_q    = (const float*)d_in[7];
    const float* Wv1      = (const float*)d_in[8];
    const float* bv1      = (const float*)d_in[9];
    const float* gnw_v1   = (const float*)d_in[10];
    const float* gnb_v1   = (const float*)d_in[11];
    const float* Wb       = (const float*)d_in[12];
    const float* bb       = (const float*)d_in[13];
    const float* Ws       = (const float*)d_in[14];
    const float* bs       = (const float*)d_in[15];
    const float* Wc       = (const float*)d_in[16];
    const float* bc       = (const float*)d_in[17];
    const float* Wt       = (const float*)d_in[18];
    const float* bt       = (const float*)d_in[19];
    const float* lnw      = (const float*)d_in[20];
    const float* lnb      = (const float*)d_in[21];
    float* out = (float*)d_out;

    float* ws      = (float*)d_ws;
    float* v1buf   = ws;                     // 64K floats
    float* attb    = ws + 65536;             // 64K
    float* parts   = ws + 131072;            // 16 x 64K = 1M floats
    short* wbq_g   = (short*)(ws + 1179648); // 512*8192 bf16 = 8 MB
    float* pool_pt = ws + 3276800;           // 2048*64
    float* esum_pt = ws + 3407872;           // 2048
    float* av_pt   = ws + 3409920;           // 2048*128

    a1_tile<<<256, 256, 0, stream>>>(h_state, Wq, Wv1, parts);
    a2b0<<<512, 256, 0, stream>>>(parts, bq, bv1, gnw_q, gnb_q, gnw_v1, gnb_v1,
                                  Wb, v1buf, wbq_g);
    b_fused<<<2048, 256, 0, stream>>>(pat, att_mask, wbq_g, bb, Ws, bs,
                                      pool_pt, esum_pt, av_pt);
    b5_final<<<512, 256, 0, stream>>>(pool_pt, esum_pt, av_pt, att_mask,
                                      Wc, bc, v1buf, attb);
    c1_tile<<<256, 256, 0, stream>>>(h_state, attb, Wt, parts);
    c2_ln<<<64, 256, 0, stream>>>(parts, bt, lnw, lnb, out);
}